// Round 2
// baseline (708.058 us; speedup 1.0000x reference)
//
#include <hip/hip_runtime.h>
#include <math.h>

#define T_ 250
#define BL 2000        // 8 * 250
#define KIN 480        // P*F = 20*24
#define NFLAT 120000   // 24*5000

__device__ __forceinline__ float sigmoidf_(float x){ return 1.0f/(1.0f+expf(-x)); }
__device__ __forceinline__ float siluf_(float x){ return x*sigmoidf_(x); }
__device__ __forceinline__ float softplusf_(float x){ return (x > 20.0f) ? x : log1pf(expf(x)); }
__device__ __forceinline__ float seluf_(float x){
  const float sc = 1.0507009873554804934193349852946f;
  const float al = 1.6732632423543772848170429916717f;
  return x > 0.0f ? sc*x : sc*al*expm1f(x);
}

// DPP-based add: x + dpp_move(x). Runs on the VALU pipe (no LDS round-trip).
template<int CTRL>
__device__ __forceinline__ float dpp_add(float x) {
  int t = __builtin_amdgcn_update_dpp(0, __builtin_bit_cast(int, x), CTRL, 0xF, 0xF, true);
  return x + __builtin_bit_cast(float, t);
}

// ---------------------------------------------------------------------------
// Generic fp32 tiled GEMM: C[M,N] = A[M,K] * W[N,K]^T  (both row-major, K contig)
// epi: 0 = store, 1 = store softplus(acc + bias[n]), 2 = store selu(acc),
//      3 = atomicAdd (for split-K; C must be pre-zeroed)
// Register double-buffered staging.
// ---------------------------------------------------------------------------
template<int BM, int BN, int BK, int TM, int TN>
__global__ __launch_bounds__(256, 2) void gemm_nt(
    const float* __restrict__ A, const float* __restrict__ W,
    float* __restrict__ C, const float* __restrict__ bias,
    int M, int N, int K, int lda, int ldb, int ldc, int epi)
{
  static_assert(BK == 32, "BK must be 32");
  __shared__ __align__(16) float As[BK][BM + 4];
  __shared__ __align__(16) float Bs[BK][BN + 4];
  constexpr int TNX = BN / TN;
  constexpr int TMX = BM / TM;
  static_assert(TNX * TMX == 256, "256 threads required");
  constexpr int AF4 = BM * BK / 1024;   // float4 loads per thread for A tile
  constexpr int BF4 = BN * BK / 1024;

  const int tid = threadIdx.x;
  const int tx = tid % TNX;
  const int ty = tid / TNX;
  const int m0 = blockIdx.y * BM;
  const int n0 = blockIdx.x * BN;
  const int kchunk = K / (int)gridDim.z;
  const int k_begin = blockIdx.z * kchunk;
  const int k_end = k_begin + kchunk;

  float4 pa[AF4], pb[BF4];

  auto fetch = [&](int k0) {
#pragma unroll
    for (int i = 0; i < AF4; ++i) {
      int fi = tid + 256 * i;
      int r = fi >> 3;               // BK/4 == 8 float4 per row
      int kc = (fi & 7) * 4;
      int m = m0 + r;
      pa[i] = (m < M) ? *(const float4*)(A + (size_t)m * lda + k0 + kc)
                      : make_float4(0.f, 0.f, 0.f, 0.f);
    }
#pragma unroll
    for (int i = 0; i < BF4; ++i) {
      int fi = tid + 256 * i;
      int r = fi >> 3;
      int kc = (fi & 7) * 4;
      int n = n0 + r;
      pb[i] = (n < N) ? *(const float4*)(W + (size_t)n * ldb + k0 + kc)
                      : make_float4(0.f, 0.f, 0.f, 0.f);
    }
  };

  fetch(k_begin);   // prologue: tile 0 into registers

  float acc[TM][TN];
#pragma unroll
  for (int i = 0; i < TM; ++i)
#pragma unroll
    for (int j = 0; j < TN; ++j) acc[i][j] = 0.0f;

  for (int k0 = k_begin; k0 < k_end; k0 += BK) {
    // registers -> LDS (previous iteration's barrier makes this safe)
#pragma unroll
    for (int i = 0; i < AF4; ++i) {
      int fi = tid + 256 * i;
      int r = fi >> 3;
      int kc = (fi & 7) * 4;
      As[kc + 0][r] = pa[i].x; As[kc + 1][r] = pa[i].y;
      As[kc + 2][r] = pa[i].z; As[kc + 3][r] = pa[i].w;
    }
#pragma unroll
    for (int i = 0; i < BF4; ++i) {
      int fi = tid + 256 * i;
      int r = fi >> 3;
      int kc = (fi & 7) * 4;
      Bs[kc + 0][r] = pb[i].x; Bs[kc + 1][r] = pb[i].y;
      Bs[kc + 2][r] = pb[i].z; Bs[kc + 3][r] = pb[i].w;
    }
    __syncthreads();
    if (k0 + BK < k_end) fetch(k0 + BK);   // overlap with FMA loop below
#pragma unroll
    for (int kk = 0; kk < BK; ++kk) {
      float a[TM], bb[TN];
      if constexpr ((TM & 3) == 0) {
#pragma unroll
        for (int t = 0; t < TM / 4; ++t) {
          float4 v = *(const float4*)&As[kk][ty * TM + t * 4];
          a[t*4+0] = v.x; a[t*4+1] = v.y; a[t*4+2] = v.z; a[t*4+3] = v.w;
        }
      } else {
#pragma unroll
        for (int i = 0; i < TM; ++i) a[i] = As[kk][ty * TM + i];
      }
      if constexpr ((TN & 3) == 0) {
#pragma unroll
        for (int t = 0; t < TN / 4; ++t) {
          float4 v = *(const float4*)&Bs[kk][tx * TN + t * 4];
          bb[t*4+0] = v.x; bb[t*4+1] = v.y; bb[t*4+2] = v.z; bb[t*4+3] = v.w;
        }
      } else {
#pragma unroll
        for (int j = 0; j < TN; ++j) bb[j] = Bs[kk][tx * TN + j];
      }
#pragma unroll
      for (int i = 0; i < TM; ++i)
#pragma unroll
        for (int j = 0; j < TN; ++j) acc[i][j] = fmaf(a[i], bb[j], acc[i][j]);
    }
    __syncthreads();
  }

#pragma unroll
  for (int i = 0; i < TM; ++i) {
    int m = m0 + ty * TM + i;
    if (m >= M) continue;
    if constexpr ((TN & 3) == 0) {
#pragma unroll
      for (int j0 = 0; j0 < TN; j0 += 4) {
        int n = n0 + tx * TN + j0;
        float v[4];
#pragma unroll
        for (int t = 0; t < 4; ++t) {
          float xv = acc[i][j0 + t];
          if (epi == 1) xv = softplusf_(xv + bias[n + t]);
          else if (epi == 2) xv = seluf_(xv);
          v[t] = xv;
        }
        if (epi == 3) {
#pragma unroll
          for (int t = 0; t < 4; ++t)
            if (n + t < N) atomicAdd(&C[(size_t)m * ldc + n + t], v[t]);
        } else if (n + 3 < N) {
          *(float4*)&C[(size_t)m * ldc + n] = make_float4(v[0], v[1], v[2], v[3]);
        } else {
#pragma unroll
          for (int t = 0; t < 4; ++t)
            if (n + t < N) C[(size_t)m * ldc + n + t] = v[t];
        }
      }
    } else {
#pragma unroll
      for (int j = 0; j < TN; ++j) {
        int n = n0 + tx * TN + j;
        if (n >= N) continue;
        float v = acc[i][j];
        if (epi == 1) v = softplusf_(v + bias[n]);
        else if (epi == 2) v = seluf_(v);
        if (epi == 3) atomicAdd(&C[(size_t)m * ldc + n], v);
        else C[(size_t)m * ldc + n] = v;
      }
    }
  }
}

// ---------------------------------------------------------------------------
// 128x128 fp32 GEMM, TM=TN=8 (1.0 LDS-byte/FMA vs 1.5 for TM4xTN8).
// Staging: each thread owns a 4x4 sub-block -> 4 float4 global loads +
// 4 ds_write_b128 (register transpose), no scattered b32 writes.
// Register double-buffered. Plain store epilogue (in_proj only).
// ---------------------------------------------------------------------------
__global__ __launch_bounds__(256, 1) void gemm_nt_big(
    const float* __restrict__ A, const float* __restrict__ W,
    float* __restrict__ C, int M, int N, int K, int lda, int ldb, int ldc)
{
  __shared__ __align__(16) float As[32][132];
  __shared__ __align__(16) float Bs[32][132];
  const int tid = threadIdx.x;
  const int tx = tid & 15;          // n-fragment group (8 cols)
  const int ty = tid >> 4;          // m-fragment group (8 rows)
  const int rg = tid & 31;          // staging row-group (4 rows)
  const int kg = tid >> 5;          // staging k-group  (4 ks)
  const int m0 = blockIdx.y * 128;
  const int n0 = blockIdx.x * 128;

  float pa[4][4], pb[4][4];         // [row-in-group][k-in-group]

  auto fetch = [&](int k0) {
#pragma unroll
    for (int i = 0; i < 4; ++i) {
      int m = m0 + rg * 4 + i;
      float4 v = make_float4(0.f, 0.f, 0.f, 0.f);
      if (m < M) v = *(const float4*)(A + (size_t)m * lda + k0 + kg * 4);
      pa[i][0] = v.x; pa[i][1] = v.y; pa[i][2] = v.z; pa[i][3] = v.w;
    }
#pragma unroll
    for (int i = 0; i < 4; ++i) {
      int n = n0 + rg * 4 + i;
      float4 v = make_float4(0.f, 0.f, 0.f, 0.f);
      if (n < N) v = *(const float4*)(W + (size_t)n * ldb + k0 + kg * 4);
      pb[i][0] = v.x; pb[i][1] = v.y; pb[i][2] = v.z; pb[i][3] = v.w;
    }
  };

  fetch(0);

  float acc[8][8];
#pragma unroll
  for (int i = 0; i < 8; ++i)
#pragma unroll
    for (int j = 0; j < 8; ++j) acc[i][j] = 0.0f;

  for (int k0 = 0; k0 < K; k0 += 32) {
#pragma unroll
    for (int j = 0; j < 4; ++j)
      *(float4*)&As[kg * 4 + j][rg * 4] =
          make_float4(pa[0][j], pa[1][j], pa[2][j], pa[3][j]);
#pragma unroll
    for (int j = 0; j < 4; ++j)
      *(float4*)&Bs[kg * 4 + j][rg * 4] =
          make_float4(pb[0][j], pb[1][j], pb[2][j], pb[3][j]);
    __syncthreads();
    if (k0 + 32 < K) fetch(k0 + 32);
#pragma unroll
    for (int kk = 0; kk < 32; ++kk) {
      float a[8], bb[8];
      float4 v0 = *(const float4*)&As[kk][ty * 8];
      float4 v1 = *(const float4*)&As[kk][ty * 8 + 4];
      a[0]=v0.x; a[1]=v0.y; a[2]=v0.z; a[3]=v0.w;
      a[4]=v1.x; a[5]=v1.y; a[6]=v1.z; a[7]=v1.w;
      float4 w0 = *(const float4*)&Bs[kk][tx * 8];
      float4 w1 = *(const float4*)&Bs[kk][tx * 8 + 4];
      bb[0]=w0.x; bb[1]=w0.y; bb[2]=w0.z; bb[3]=w0.w;
      bb[4]=w1.x; bb[5]=w1.y; bb[6]=w1.z; bb[7]=w1.w;
#pragma unroll
      for (int i = 0; i < 8; ++i)
#pragma unroll
        for (int j = 0; j < 8; ++j) acc[i][j] = fmaf(a[i], bb[j], acc[i][j]);
    }
    __syncthreads();
  }

#pragma unroll
  for (int i = 0; i < 8; ++i) {
    int m = m0 + ty * 8 + i;
    if (m >= M) continue;
#pragma unroll
    for (int j0 = 0; j0 < 8; j0 += 4) {
      int n = n0 + tx * 8 + j0;
      if (n + 3 < N) {
        *(float4*)&C[(size_t)m * ldc + n] =
            make_float4(acc[i][j0], acc[i][j0+1], acc[i][j0+2], acc[i][j0+3]);
      } else {
#pragma unroll
        for (int t = 0; t < 4; ++t)
          if (n + t < N) C[(size_t)m * ldc + n + t] = acc[i][j0 + t];
      }
    }
  }
}

// ---------------------------------------------------------------------------
// Depthwise causal conv1d (width 4) + bias + silu -> xc.
// ALSO replaces the z-half of xz with silu(z) in place (scan consumes it raw).
// ---------------------------------------------------------------------------
__global__ __launch_bounds__(256) void conv_silu(
    float* __restrict__ xz, const float* __restrict__ cw,
    const float* __restrict__ cb, float* __restrict__ xc)
{
  int id = blockIdx.x * 256 + threadIdx.x;
  if (id >= BL * 1024) return;
  int bl = id >> 10;
  int d = id & 1023;
  int l = bl % T_;
  float4 w4 = *(const float4*)(cw + d * 4);
  float s = cb[d];
  if (l >= 3) s = fmaf(xz[(size_t)(bl - 3) * 2048 + d], w4.x, s);
  if (l >= 2) s = fmaf(xz[(size_t)(bl - 2) * 2048 + d], w4.y, s);
  if (l >= 1) s = fmaf(xz[(size_t)(bl - 1) * 2048 + d], w4.z, s);
  s = fmaf(xz[(size_t)bl * 2048 + d], w4.w, s);
  xc[id] = siluf_(s);
  float z = xz[(size_t)bl * 2048 + 1024 + d];
  xz[(size_t)bl * 2048 + 1024 + d] = siluf_(z);
}

// ---------------------------------------------------------------------------
// Selective scan v4. Wave = 2 channels x (32 lanes x 2 states). 4096 waves.
// DPP reduction; depth-4 prefetch; reads precomputed silu(z).
// ---------------------------------------------------------------------------
__global__ __launch_bounds__(256) void scan_kernel(
    const float* __restrict__ dtb, const float* __restrict__ xc,
    const float* __restrict__ xdbl, float* __restrict__ xz,
    const float* __restrict__ A_log, const float* __restrict__ Dp)
{
  int tid = threadIdx.x;
  int wv = tid >> 6, lane = tid & 63;
  int c = lane >> 5;          // channel within the pair
  int u = lane & 31;          // state-pair index (states 2u, 2u+1)
  int w = blockIdx.x * 4 + wv;    // 0..4095
  int b = w >> 9;                 // batch
  int d = ((w & 511) << 1) + c;   // channel
  const float LOG2E = 1.4426950408889634f;
  float2 al = *(const float2*)(A_log + (size_t)d * 64 + u * 2);
  float am0 = -expf(al.x) * LOG2E;
  float am1 = -expf(al.y) * LOG2E;
  float Dv = Dp[d];
  float h0 = 0.f, h1 = 0.f;
  const float* dtp = dtb + (size_t)b * 256000 + d;
  const float* xp  = xc  + (size_t)b * 256000 + d;
  const float* zp  = xz  + (size_t)b * 512000 + 1024 + d;   // silu(z)
  float*       yp  = xz  + (size_t)b * 512000 + d;
  const float* bp  = xdbl + (size_t)b * 40000 + 32 + u * 2;
  const float* cp  = bp + 64;

  float dt_f[4], xv_f[4], sz_f[4];
  float2 B_f[4], C_f[4];
#pragma unroll
  for (int i = 0; i < 4; ++i) {
    dt_f[i] = dtp[(size_t)i * 1024];
    xv_f[i] = xp[(size_t)i * 1024];
    sz_f[i] = zp[(size_t)i * 2048];
    B_f[i] = *(const float2*)(bp + (size_t)i * 160);
    C_f[i] = *(const float2*)(cp + (size_t)i * 160);
  }
  const bool outlane = (u == 16);   // lanes 16 and 48

#pragma unroll 4
  for (int l = 0; l < 252; ++l) {
    int slot = l & 3;
    float dt = dt_f[slot], xv = xv_f[slot], sz = sz_f[slot];
    float2 Bv = B_f[slot], Cv = C_f[slot];
    // prefetch step l+4 (unconditional; overreads stay inside d_ws)
    dt_f[slot] = dtp[(size_t)(l + 4) * 1024];
    xv_f[slot] = xp[(size_t)(l + 4) * 1024];
    sz_f[slot] = zp[(size_t)(l + 4) * 2048];
    B_f[slot]  = *(const float2*)(bp + (size_t)(l + 4) * 160);
    C_f[slot]  = *(const float2*)(cp + (size_t)(l + 4) * 160);

    float dtx = dt * xv;
    h0 = fmaf(h0, exp2f(dt * am0), dtx * Bv.x);
    h1 = fmaf(h1, exp2f(dt * am1), dtx * Bv.y);
    float p = fmaf(h1, Cv.y, h0 * Cv.x);
    p = dpp_add<0xB1>(p);    // xor 1
    p = dpp_add<0x4E>(p);    // xor 2
    p = dpp_add<0x124>(p);   // row_ror:4
    p = dpp_add<0x128>(p);   // row_ror:8  -> row sums in all 16 lanes
    p = dpp_add<0x142>(p);   // row_bcast15 -> ch totals on lanes 16-31 / 48-63
    if (outlane && l < T_) yp[(size_t)l * 2048] = fmaf(xv, Dv, p) * sz;
  }
}

// ---------------------------------------------------------------------------
// selu + permute ym[2000][480] -> yfl [8][120000] (f-major)
// ---------------------------------------------------------------------------
__global__ __launch_bounds__(256) void transpose_selu(
    const float* __restrict__ ym, float* __restrict__ yfl)
{
  int id = blockIdx.x * 256 + threadIdx.x;
  if (id >= 8 * NFLAT) return;
  int b = id / NFLAT;
  int r = id % NFLAT;
  int f = r / 5000;
  int qq = r % 5000;
  int tt = qq / 20;
  int p = qq % 20;
  yfl[id] = seluf_(ym[(size_t)(b * T_ + tt) * KIN + p * 24 + f]);
}

// ---------------------------------------------------------------------------
// fc1: r1[b][c] += sum_k yfl[b][k] * W1[c][k].
// ---------------------------------------------------------------------------
__global__ __launch_bounds__(256) void fc1_kernel(
    const float* __restrict__ yfl, const float* __restrict__ W,
    float* __restrict__ r1)
{
  int blk = blockIdx.x;
  int ks = blk % 24;           // k-slice: [ks*5000, ks*5000+5000)
  int cg = blk / 24;           // 0..31
  int wv = threadIdx.x >> 6;
  int lane = threadIdx.x & 63;
  int c0 = cg * 16 + wv * 4;
  const float* W0 = W + (size_t)c0 * NFLAT;
  float acc[4][8];
#pragma unroll
  for (int cc = 0; cc < 4; ++cc)
#pragma unroll
    for (int b = 0; b < 8; ++b) acc[cc][b] = 0.0f;

  int kbase = ks * 5000;
  int kend = kbase + 5000;
  for (int k = kbase + lane * 4; k + 4 <= kend; k += 256) {
    float4 w0 = *(const float4*)(W0 + k);
    float4 w1 = *(const float4*)(W0 + NFLAT + k);
    float4 w2 = *(const float4*)(W0 + 2 * (size_t)NFLAT + k);
    float4 w3 = *(const float4*)(W0 + 3 * (size_t)NFLAT + k);
#pragma unroll
    for (int b = 0; b < 8; ++b) {
      float4 y = *(const float4*)(yfl + (size_t)b * NFLAT + k);
      acc[0][b] = fmaf(w0.x, y.x, fmaf(w0.y, y.y, fmaf(w0.z, y.z, fmaf(w0.w, y.w, acc[0][b]))));
      acc[1][b] = fmaf(w1.x, y.x, fmaf(w1.y, y.y, fmaf(w1.z, y.z, fmaf(w1.w, y.w, acc[1][b]))));
      acc[2][b] = fmaf(w2.x, y.x, fmaf(w2.y, y.y, fmaf(w2.z, y.z, fmaf(w2.w, y.w, acc[2][b]))));
      acc[3][b] = fmaf(w3.x, y.x, fmaf(w3.y, y.y, fmaf(w3.z, y.z, fmaf(w3.w, y.w, acc[3][b]))));
    }
  }
#pragma unroll
  for (int cc = 0; cc < 4; ++cc)
#pragma unroll
    for (int b = 0; b < 8; ++b) {
      float s = acc[cc][b];
      s += __shfl_xor(s, 1);
      s += __shfl_xor(s, 2);
      s += __shfl_xor(s, 4);
      s += __shfl_xor(s, 8);
      s += __shfl_xor(s, 16);
      s += __shfl_xor(s, 32);
      if (lane == 0) atomicAdd(&r1[b * 512 + c0 + cc], s);
    }
}

// ---------------------------------------------------------------------------
// fc2: one wave per output (b,j): dot-512 + biases
// ---------------------------------------------------------------------------
__global__ __launch_bounds__(256) void fc2_kernel(
    const float* __restrict__ r1, const float* __restrict__ b1,
    const float* __restrict__ W2, const float* __restrict__ b2,
    float* __restrict__ r2)
{
  int wid = blockIdx.x * 4 + (threadIdx.x >> 6);   // 0..2047
  int lane = threadIdx.x & 63;
  int b = wid >> 8;
  int j = wid & 255;
  int off = lane * 8;
  float4 ya = *(const float4*)(r1 + b * 512 + off);
  float4 yb = *(const float4*)(r1 + b * 512 + off + 4);
  float4 ba = *(const float4*)(b1 + off);
  float4 bbv = *(const float4*)(b1 + off + 4);
  float4 wa = *(const float4*)(W2 + (size_t)j * 512 + off);
  float4 wb = *(const float4*)(W2 + (size_t)j * 512 + off + 4);
  float p = (ya.x + ba.x) * wa.x + (ya.y + ba.y) * wa.y +
            (ya.z + ba.z) * wa.z + (ya.w + ba.w) * wa.w +
            (yb.x + bbv.x) * wb.x + (yb.y + bbv.y) * wb.y +
            (yb.z + bbv.z) * wb.z + (yb.w + bbv.w) * wb.w;
  p += __shfl_xor(p, 1);
  p += __shfl_xor(p, 2);
  p += __shfl_xor(p, 4);
  p += __shfl_xor(p, 8);
  p += __shfl_xor(p, 16);
  p += __shfl_xor(p, 32);
  if (lane == 0) r2[b * 256 + j] = p + b2[j];
}

// ---------------------------------------------------------------------------
// fc3 + fc4 fused, single block
// ---------------------------------------------------------------------------
__global__ __launch_bounds__(256) void fc34_kernel(
    const float* __restrict__ r2, const float* __restrict__ W3,
    const float* __restrict__ b3, const float* __restrict__ W4,
    const float* __restrict__ b4, float* __restrict__ out)
{
  __shared__ float a3[512];
  int tid = threadIdx.x;
  for (int o = tid; o < 512; o += 256) {
    int b = o >> 6, j = o & 63;
    float s = b3[j];
    const float* rr = r2 + b * 256;
    const float* wr = W3 + j * 256;
    for (int c = 0; c < 256; c += 4) {
      float4 rv = *(const float4*)(rr + c);
      float4 wv = *(const float4*)(wr + c);
      s = fmaf(rv.x, wv.x, fmaf(rv.y, wv.y, fmaf(rv.z, wv.z, fmaf(rv.w, wv.w, s))));
    }
    a3[o] = s;
  }
  __syncthreads();
  if (tid < 64) {
    int b = tid >> 3, j = tid & 7;
    float s = b4[j];
    const float* ar = a3 + b * 64;
    const float* wr = W4 + j * 64;
    for (int c = 0; c < 64; ++c) s = fmaf(ar[c], wr[c], s);
    out[b * 8 + j] = s;
  }
}

// ---------------------------------------------------------------------------
extern "C" void kernel_launch(void* const* d_in, const int* in_sizes, int n_in,
                              void* d_out, int out_size, void* d_ws, size_t ws_size,
                              hipStream_t stream) {
  const float* x      = (const float*)d_in[0];   // [8,5000,24] == [2000][480]
  const float* w_in   = (const float*)d_in[1];   // [2048,512]
  const float* conv_w = (const float*)d_in[2];   // [1024,4]
  const float* conv_b = (const float*)d_in[3];   // [1024]
  const float* w_xp   = (const float*)d_in[4];   // [160,1024]
  const float* w_dt   = (const float*)d_in[5];   // [1024,32]
  const float* b_dt   = (const float*)d_in[6];   // [1024]
  const float* A_log  = (const float*)d_in[7];   // [1024,64]
  const float* Dp     = (const float*)d_in[8];   // [1024]
  const float* w_out  = (const float*)d_in[9];   // [512,1024]
  const float* w1 = (const float*)d_in[10];      // [512,120000]
  const float* b1 = (const float*)d_in[11];
  const float* w2 = (const float*)d_in[12];      // [256,512]
  const float* b2 = (const float*)d_in[13];
  const float* w3 = (const float*)d_in[14];      // [64,256]
  const float* b3 = (const float*)d_in[15];
  const float* w4 = (const float*)d_in[16];      // [8,64]
  const float* b4 = (const float*)d_in[17];
  float* out = (float*)d_out;

  float* ws   = (float*)d_ws;
  float* xz   = ws;                 // [2000][2048]  (x half -> gated y; z half -> silu(z))
  float* xc   = xz + 4096000;       // [2000][1024]
  float* dtb  = xc + 2048000;       // [2000][1024]
  float* yfl  = dtb + 2048000;      // [8][120000]
  float* xdbl = yfl + 960000;       // [2000][160]   (atomic)
  float* r1   = xdbl + 320000;      // [8][512]      (atomic)
  float* r2   = r1 + 4096;          // [8][256]
  float* ym   = r2 + 2048;          // [2000][480]   (atomic, split-K out_proj)

  // zero the atomic accumulators: xdbl + r1 + r2 + ym, contiguous
  hipMemsetAsync(xdbl, 0, (320000 + 4096 + 2048 + 960000) * sizeof(float), stream);

  // 1. in_proj (128x128 tile, TM=TN=8): xz[2000][2048] = x @ Win^T
  gemm_nt_big<<<dim3(2048 / 128, (BL + 127) / 128, 1), 256, 0, stream>>>(
      x, w_in, xz, BL, 2048, KIN, KIN, 512, 2048);

  // 2. depthwise conv + silu (also silu's the z-half in place)
  conv_silu<<<(BL * 1024) / 256, 256, 0, stream>>>(xz, conv_w, conv_b, xc);

  // 3. x_proj (split-K=4, atomic): xdbl[2000][160] = xc @ Wxp^T
  gemm_nt<64, 64, 32, 4, 4><<<dim3(3, (BL + 63) / 64, 4), 256, 0, stream>>>(
      xc, w_xp, xdbl, nullptr, BL, 160, 1024, 1024, 1024, 160, 3);

  // 4. dt_proj + softplus: dtb[2000][1024] = softplus(xdbl[:, :32] @ Wdt^T + b_dt)
  gemm_nt<32, 64, 32, 1, 8><<<dim3(1024 / 64, (BL + 31) / 32, 1), 256, 0, stream>>>(
      xdbl, w_dt, dtb, b_dt, BL, 1024, 32, 160, 32, 1024, 1);

  // 5. selective scan -> gated y into xz x-half
  scan_kernel<<<1024, 256, 0, stream>>>(dtb, xc, xdbl, xz, A_log, Dp);

  // 6. out_proj (split-K=4, atomic into ym)
  gemm_nt<64, 64, 32, 4, 4><<<dim3((KIN + 63) / 64, (BL + 63) / 64, 4), 256, 0, stream>>>(
      xz, w_out, ym, nullptr, BL, KIN, 1024, 2048, 1024, KIN, 3);

  // 7. selu + permute to y_flat
  transpose_selu<<<(8 * NFLAT) / 256, 256, 0, stream>>>(ym, yfl);

  // 8. fc1 (atomic accumulate into r1)
  fc1_kernel<<<768, 256, 0, stream>>>(yfl, w1, r1);

  // 9. fc2
  fc2_kernel<<<512, 256, 0, stream>>>(r1, b1, w2, b2, r2);

  // 10. fc3 + fc4
  fc34_kernel<<<1, 256, 0, stream>>>(r2, w3, b3, w4, b4, out);
}

// Round 3
// 645.943 us; speedup vs baseline: 1.0962x; 1.0962x over previous
//
#include <hip/hip_runtime.h>
#include <math.h>

#define T_ 250
#define BL 2000        // 8 * 250
#define KIN 480        // P*F = 20*24
#define NFLAT 120000   // 24*5000

typedef __attribute__((ext_vector_type(8))) short short8;
typedef __attribute__((ext_vector_type(4))) float f32x4;

__device__ __forceinline__ float sigmoidf_(float x){ return 1.0f/(1.0f+expf(-x)); }
__device__ __forceinline__ float siluf_(float x){ return x*sigmoidf_(x); }
__device__ __forceinline__ float softplusf_(float x){ return (x > 20.0f) ? x : log1pf(expf(x)); }
__device__ __forceinline__ float seluf_(float x){
  const float sc = 1.0507009873554804934193349852946f;
  const float al = 1.6732632423543772848170429916717f;
  return x > 0.0f ? sc*x : sc*al*expm1f(x);
}
__device__ __forceinline__ unsigned f2bf(float f){   // fp32 -> bf16 bits, RNE
  unsigned u = __builtin_bit_cast(unsigned, f);
  return (u + 0x7FFFu + ((u >> 16) & 1u)) >> 16;
}

// DPP-based add: x + dpp_move(x). Runs on the VALU pipe (no LDS round-trip).
template<int CTRL>
__device__ __forceinline__ float dpp_add(float x) {
  int t = __builtin_amdgcn_update_dpp(0, __builtin_bit_cast(int, x), CTRL, 0xF, 0xF, true);
  return x + __builtin_bit_cast(float, t);
}

// ---------------------------------------------------------------------------
// in_proj via bf16 MFMA: C[2000][2048] = x[2000][480] @ W[2048][512]^T
// (x's k>=480 pad is zero in the reference, so K truncates to 480 = 15*32.)
// 128x128 tile, 4 waves, each wave a 64x64 sub-tile = 4x4 MFMA 16x16x32 frags.
// LDS tiles bf16 [128][40] (pitch 80B: even 8-lane spread per bank cluster for
// both the b128 fragment reads and the staging writes).
// Register double-buffered staging (fetch k0+32 during MFMA of k0).
// ---------------------------------------------------------------------------
__global__ __launch_bounds__(256) void inproj_mfma(
    const float* __restrict__ x, const float* __restrict__ w,
    float* __restrict__ C)
{
  __shared__ __align__(16) unsigned short As[128 * 40];
  __shared__ __align__(16) unsigned short Bs[128 * 40];
  const int tid = threadIdx.x;
  const int m0 = blockIdx.y * 128;
  const int n0 = blockIdx.x * 128;
  const int wid = tid >> 6, lane = tid & 63;
  const int wr = wid >> 1, wc = wid & 1;     // wave sub-tile (64 rows, 64 cols)
  const int sr = tid >> 1;                   // staging row 0..127
  const int sk = (tid & 1) * 16;             // staging k offset (0 or 16)
  const int fr = lane & 15, fg = lane >> 4;  // fragment row/col + k-group

  float4 pa[4], pb[4];
  auto fetch = [&](int k0) {
    int m = m0 + sr;
    if (m < BL) {
      const float* xp = x + (size_t)m * KIN + k0 + sk;
      pa[0] = *(const float4*)(xp);
      pa[1] = *(const float4*)(xp + 4);
      pa[2] = *(const float4*)(xp + 8);
      pa[3] = *(const float4*)(xp + 12);
    } else {
      pa[0] = pa[1] = pa[2] = pa[3] = make_float4(0.f, 0.f, 0.f, 0.f);
    }
    const float* wp = w + (size_t)(n0 + sr) * 512 + k0 + sk;
    pb[0] = *(const float4*)(wp);
    pb[1] = *(const float4*)(wp + 4);
    pb[2] = *(const float4*)(wp + 8);
    pb[3] = *(const float4*)(wp + 12);
  };
  auto pack2 = [](float a, float b) {
    return f2bf(a) | (f2bf(b) << 16);
  };
  auto stash = [&](unsigned short* S, float4* p) {
    uint4 lo = make_uint4(pack2(p[0].x, p[0].y), pack2(p[0].z, p[0].w),
                          pack2(p[1].x, p[1].y), pack2(p[1].z, p[1].w));
    uint4 hi = make_uint4(pack2(p[2].x, p[2].y), pack2(p[2].z, p[2].w),
                          pack2(p[3].x, p[3].y), pack2(p[3].z, p[3].w));
    *(uint4*)&S[sr * 40 + sk] = lo;        // sr*40 ushorts = 80B (16B-aligned)
    *(uint4*)&S[sr * 40 + sk + 8] = hi;
  };

  f32x4 acc[4][4];
#pragma unroll
  for (int i = 0; i < 4; ++i)
#pragma unroll
    for (int j = 0; j < 4; ++j) acc[i][j] = (f32x4)(0.0f);

  fetch(0);
  for (int k0 = 0; k0 < KIN; k0 += 32) {
    stash(As, pa);
    stash(Bs, pb);
    __syncthreads();
    if (k0 + 32 < KIN) fetch(k0 + 32);
    short8 av[4], bv[4];
#pragma unroll
    for (int fi = 0; fi < 4; ++fi)
      av[fi] = *(const short8*)&As[(wr * 64 + fi * 16 + fr) * 40 + fg * 8];
#pragma unroll
    for (int fj = 0; fj < 4; ++fj)
      bv[fj] = *(const short8*)&Bs[(wc * 64 + fj * 16 + fr) * 40 + fg * 8];
#pragma unroll
    for (int fi = 0; fi < 4; ++fi)
#pragma unroll
      for (int fj = 0; fj < 4; ++fj)
        acc[fi][fj] = __builtin_amdgcn_mfma_f32_16x16x32_bf16(
            av[fi], bv[fj], acc[fi][fj], 0, 0, 0);
    __syncthreads();
  }

  // C/D layout: col = lane&15, row = (lane>>4)*4 + reg  [guide-verified]
#pragma unroll
  for (int fi = 0; fi < 4; ++fi) {
    int row = m0 + wr * 64 + fi * 16 + fg * 4;
#pragma unroll
    for (int fj = 0; fj < 4; ++fj) {
      int col = n0 + wc * 64 + fj * 16 + fr;
#pragma unroll
      for (int r = 0; r < 4; ++r)
        if (row + r < BL) C[(size_t)(row + r) * 2048 + col] = acc[fi][fj][r];
    }
  }
}

// ---------------------------------------------------------------------------
// Generic fp32 tiled GEMM: C[M,N] = A[M,K] * W[N,K]^T  (both row-major, K contig)
// epi: 0 = store, 1 = store softplus(acc + bias[n]), 2 = store selu(acc),
//      3 = atomicAdd (split-K; C pre-zeroed),
//      4 = selu + mamba-transpose store into yfl [8][24][250][20] layout
// Register double-buffered staging.
// ---------------------------------------------------------------------------
template<int BM, int BN, int BK, int TM, int TN>
__global__ __launch_bounds__(256, 2) void gemm_nt(
    const float* __restrict__ A, const float* __restrict__ W,
    float* __restrict__ C, const float* __restrict__ bias,
    int M, int N, int K, int lda, int ldb, int ldc, int epi)
{
  static_assert(BK == 32, "BK must be 32");
  __shared__ __align__(16) float As[BK][BM + 4];
  __shared__ __align__(16) float Bs[BK][BN + 4];
  constexpr int TNX = BN / TN;
  constexpr int TMX = BM / TM;
  static_assert(TNX * TMX == 256, "256 threads required");
  constexpr int AF4 = BM * BK / 1024;
  constexpr int BF4 = BN * BK / 1024;

  const int tid = threadIdx.x;
  const int tx = tid % TNX;
  const int ty = tid / TNX;
  const int m0 = blockIdx.y * BM;
  const int n0 = blockIdx.x * BN;
  const int kchunk = K / (int)gridDim.z;
  const int k_begin = blockIdx.z * kchunk;
  const int k_end = k_begin + kchunk;

  float4 pa[AF4], pb[BF4];

  auto fetch = [&](int k0) {
#pragma unroll
    for (int i = 0; i < AF4; ++i) {
      int fi = tid + 256 * i;
      int r = fi >> 3;
      int kc = (fi & 7) * 4;
      int m = m0 + r;
      pa[i] = (m < M) ? *(const float4*)(A + (size_t)m * lda + k0 + kc)
                      : make_float4(0.f, 0.f, 0.f, 0.f);
    }
#pragma unroll
    for (int i = 0; i < BF4; ++i) {
      int fi = tid + 256 * i;
      int r = fi >> 3;
      int kc = (fi & 7) * 4;
      int n = n0 + r;
      pb[i] = (n < N) ? *(const float4*)(W + (size_t)n * ldb + k0 + kc)
                      : make_float4(0.f, 0.f, 0.f, 0.f);
    }
  };

  fetch(k_begin);

  float acc[TM][TN];
#pragma unroll
  for (int i = 0; i < TM; ++i)
#pragma unroll
    for (int j = 0; j < TN; ++j) acc[i][j] = 0.0f;

  for (int k0 = k_begin; k0 < k_end; k0 += BK) {
#pragma unroll
    for (int i = 0; i < AF4; ++i) {
      int fi = tid + 256 * i;
      int r = fi >> 3;
      int kc = (fi & 7) * 4;
      As[kc + 0][r] = pa[i].x; As[kc + 1][r] = pa[i].y;
      As[kc + 2][r] = pa[i].z; As[kc + 3][r] = pa[i].w;
    }
#pragma unroll
    for (int i = 0; i < BF4; ++i) {
      int fi = tid + 256 * i;
      int r = fi >> 3;
      int kc = (fi & 7) * 4;
      Bs[kc + 0][r] = pb[i].x; Bs[kc + 1][r] = pb[i].y;
      Bs[kc + 2][r] = pb[i].z; Bs[kc + 3][r] = pb[i].w;
    }
    __syncthreads();
    if (k0 + BK < k_end) fetch(k0 + BK);
#pragma unroll
    for (int kk = 0; kk < BK; ++kk) {
      float a[TM], bb[TN];
      if constexpr ((TM & 3) == 0) {
#pragma unroll
        for (int t = 0; t < TM / 4; ++t) {
          float4 v = *(const float4*)&As[kk][ty * TM + t * 4];
          a[t*4+0] = v.x; a[t*4+1] = v.y; a[t*4+2] = v.z; a[t*4+3] = v.w;
        }
      } else {
#pragma unroll
        for (int i = 0; i < TM; ++i) a[i] = As[kk][ty * TM + i];
      }
      if constexpr ((TN & 3) == 0) {
#pragma unroll
        for (int t = 0; t < TN / 4; ++t) {
          float4 v = *(const float4*)&Bs[kk][tx * TN + t * 4];
          bb[t*4+0] = v.x; bb[t*4+1] = v.y; bb[t*4+2] = v.z; bb[t*4+3] = v.w;
        }
      } else {
#pragma unroll
        for (int j = 0; j < TN; ++j) bb[j] = Bs[kk][tx * TN + j];
      }
#pragma unroll
      for (int i = 0; i < TM; ++i)
#pragma unroll
        for (int j = 0; j < TN; ++j) acc[i][j] = fmaf(a[i], bb[j], acc[i][j]);
    }
    __syncthreads();
  }

  if (epi == 4) {
    // out_proj fused epilogue: selu + permute into yfl[b][f*5000 + tt*20 + p]
#pragma unroll
    for (int i = 0; i < TM; ++i) {
      int m = m0 + ty * TM + i;
      if (m >= M) continue;
      int b = m / 250;
      int tt = m - b * 250;
#pragma unroll
      for (int j = 0; j < TN; ++j) {
        int n = n0 + tx * TN + j;
        if (n >= N) continue;
        int p = n / 24;
        int f = n - p * 24;
        C[(size_t)b * NFLAT + (size_t)f * 5000 + tt * 20 + p] = seluf_(acc[i][j]);
      }
    }
    return;
  }

#pragma unroll
  for (int i = 0; i < TM; ++i) {
    int m = m0 + ty * TM + i;
    if (m >= M) continue;
    if constexpr ((TN & 3) == 0) {
#pragma unroll
      for (int j0 = 0; j0 < TN; j0 += 4) {
        int n = n0 + tx * TN + j0;
        float v[4];
#pragma unroll
        for (int t = 0; t < 4; ++t) {
          float xv = acc[i][j0 + t];
          if (epi == 1) xv = softplusf_(xv + bias[n + t]);
          else if (epi == 2) xv = seluf_(xv);
          v[t] = xv;
        }
        if (epi == 3) {
#pragma unroll
          for (int t = 0; t < 4; ++t)
            if (n + t < N) atomicAdd(&C[(size_t)m * ldc + n + t], v[t]);
        } else if (n + 3 < N) {
          *(float4*)&C[(size_t)m * ldc + n] = make_float4(v[0], v[1], v[2], v[3]);
        } else {
#pragma unroll
          for (int t = 0; t < 4; ++t)
            if (n + t < N) C[(size_t)m * ldc + n + t] = v[t];
        }
      }
    } else {
#pragma unroll
      for (int j = 0; j < TN; ++j) {
        int n = n0 + tx * TN + j;
        if (n >= N) continue;
        float v = acc[i][j];
        if (epi == 1) v = softplusf_(v + bias[n]);
        else if (epi == 2) v = seluf_(v);
        if (epi == 3) atomicAdd(&C[(size_t)m * ldc + n], v);
        else C[(size_t)m * ldc + n] = v;
      }
    }
  }
}

// ---------------------------------------------------------------------------
// Depthwise causal conv1d (width 4) + bias + silu -> xc, float4-vectorized
// (4 channels per thread). ALSO silu's the z-half of xz in place.
// ---------------------------------------------------------------------------
__global__ __launch_bounds__(256) void conv_silu(
    float* __restrict__ xz, const float* __restrict__ cw,
    const float* __restrict__ cb, float* __restrict__ xc)
{
  int id = blockIdx.x * 256 + threadIdx.x;
  if (id >= BL * 256) return;
  int bl = id >> 8;
  int d4 = (id & 255) * 4;
  int l = bl % T_;
  float* base = xz + (size_t)bl * 2048 + d4;
  float4 x0 = *(const float4*)(base);
  float4 x1 = (l >= 1) ? *(const float4*)(base - 2048) : make_float4(0.f,0.f,0.f,0.f);
  float4 x2 = (l >= 2) ? *(const float4*)(base - 4096) : make_float4(0.f,0.f,0.f,0.f);
  float4 x3 = (l >= 3) ? *(const float4*)(base - 6144) : make_float4(0.f,0.f,0.f,0.f);
  float4 w0 = *(const float4*)(cw + (size_t)d4 * 4);        // row d4:  [w0..w3]
  float4 w1 = *(const float4*)(cw + (size_t)d4 * 4 + 4);
  float4 w2 = *(const float4*)(cw + (size_t)d4 * 4 + 8);
  float4 w3 = *(const float4*)(cw + (size_t)d4 * 4 + 12);
  float4 cbv = *(const float4*)(cb + d4);
  float4 o;
  o.x = siluf_(fmaf(x3.x, w0.x, fmaf(x2.x, w0.y, fmaf(x1.x, w0.z, fmaf(x0.x, w0.w, cbv.x)))));
  o.y = siluf_(fmaf(x3.y, w1.x, fmaf(x2.y, w1.y, fmaf(x1.y, w1.z, fmaf(x0.y, w1.w, cbv.y)))));
  o.z = siluf_(fmaf(x3.z, w2.x, fmaf(x2.z, w2.y, fmaf(x1.z, w2.z, fmaf(x0.z, w2.w, cbv.z)))));
  o.w = siluf_(fmaf(x3.w, w3.x, fmaf(x2.w, w3.y, fmaf(x1.w, w3.z, fmaf(x0.w, w3.w, cbv.w)))));
  *(float4*)(xc + (size_t)bl * 1024 + d4) = o;
  float4 zv = *(const float4*)(base + 1024);
  zv.x = siluf_(zv.x); zv.y = siluf_(zv.y); zv.z = siluf_(zv.z); zv.w = siluf_(zv.w);
  *(float4*)(base + 1024) = zv;
}

// ---------------------------------------------------------------------------
// Selective scan v4. Wave = 2 channels x (32 lanes x 2 states). 4096 waves.
// DPP reduction; depth-4 prefetch; reads precomputed silu(z).
// ---------------------------------------------------------------------------
__global__ __launch_bounds__(256) void scan_kernel(
    const float* __restrict__ dtb, const float* __restrict__ xc,
    const float* __restrict__ xdbl, float* __restrict__ xz,
    const float* __restrict__ A_log, const float* __restrict__ Dp)
{
  int tid = threadIdx.x;
  int wv = tid >> 6, lane = tid & 63;
  int c = lane >> 5;
  int u = lane & 31;
  int w = blockIdx.x * 4 + wv;
  int b = w >> 9;
  int d = ((w & 511) << 1) + c;
  const float LOG2E = 1.4426950408889634f;
  float2 al = *(const float2*)(A_log + (size_t)d * 64 + u * 2);
  float am0 = -expf(al.x) * LOG2E;
  float am1 = -expf(al.y) * LOG2E;
  float Dv = Dp[d];
  float h0 = 0.f, h1 = 0.f;
  const float* dtp = dtb + (size_t)b * 256000 + d;
  const float* xp  = xc  + (size_t)b * 256000 + d;
  const float* zp  = xz  + (size_t)b * 512000 + 1024 + d;
  float*       yp  = xz  + (size_t)b * 512000 + d;
  const float* bp  = xdbl + (size_t)b * 40000 + 32 + u * 2;
  const float* cp  = bp + 64;

  float dt_f[4], xv_f[4], sz_f[4];
  float2 B_f[4], C_f[4];
#pragma unroll
  for (int i = 0; i < 4; ++i) {
    dt_f[i] = dtp[(size_t)i * 1024];
    xv_f[i] = xp[(size_t)i * 1024];
    sz_f[i] = zp[(size_t)i * 2048];
    B_f[i] = *(const float2*)(bp + (size_t)i * 160);
    C_f[i] = *(const float2*)(cp + (size_t)i * 160);
  }
  const bool outlane = (u == 16);

#pragma unroll 4
  for (int l = 0; l < 252; ++l) {
    int slot = l & 3;
    float dt = dt_f[slot], xv = xv_f[slot], sz = sz_f[slot];
    float2 Bv = B_f[slot], Cv = C_f[slot];
    dt_f[slot] = dtp[(size_t)(l + 4) * 1024];
    xv_f[slot] = xp[(size_t)(l + 4) * 1024];
    sz_f[slot] = zp[(size_t)(l + 4) * 2048];
    B_f[slot]  = *(const float2*)(bp + (size_t)(l + 4) * 160);
    C_f[slot]  = *(const float2*)(cp + (size_t)(l + 4) * 160);

    float dtx = dt * xv;
    h0 = fmaf(h0, exp2f(dt * am0), dtx * Bv.x);
    h1 = fmaf(h1, exp2f(dt * am1), dtx * Bv.y);
    float p = fmaf(h1, Cv.y, h0 * Cv.x);
    p = dpp_add<0xB1>(p);
    p = dpp_add<0x4E>(p);
    p = dpp_add<0x124>(p);
    p = dpp_add<0x128>(p);
    p = dpp_add<0x142>(p);
    if (outlane && l < T_) yp[(size_t)l * 2048] = fmaf(xv, Dv, p) * sz;
  }
}

// ---------------------------------------------------------------------------
// fc1: r1[b][c] += sum_k yfl[b][k] * W1[c][k].
// ---------------------------------------------------------------------------
__global__ __launch_bounds__(256) void fc1_kernel(
    const float* __restrict__ yfl, const float* __restrict__ W,
    float* __restrict__ r1)
{
  int blk = blockIdx.x;
  int ks = blk % 24;
  int cg = blk / 24;
  int wv = threadIdx.x >> 6;
  int lane = threadIdx.x & 63;
  int c0 = cg * 16 + wv * 4;
  const float* W0 = W + (size_t)c0 * NFLAT;
  float acc[4][8];
#pragma unroll
  for (int cc = 0; cc < 4; ++cc)
#pragma unroll
    for (int b = 0; b < 8; ++b) acc[cc][b] = 0.0f;

  int kbase = ks * 5000;
  int kend = kbase + 5000;
  for (int k = kbase + lane * 4; k + 4 <= kend; k += 256) {
    float4 w0 = *(const float4*)(W0 + k);
    float4 w1 = *(const float4*)(W0 + NFLAT + k);
    float4 w2 = *(const float4*)(W0 + 2 * (size_t)NFLAT + k);
    float4 w3 = *(const float4*)(W0 + 3 * (size_t)NFLAT + k);
#pragma unroll
    for (int b = 0; b < 8; ++b) {
      float4 y = *(const float4*)(yfl + (size_t)b * NFLAT + k);
      acc[0][b] = fmaf(w0.x, y.x, fmaf(w0.y, y.y, fmaf(w0.z, y.z, fmaf(w0.w, y.w, acc[0][b]))));
      acc[1][b] = fmaf(w1.x, y.x, fmaf(w1.y, y.y, fmaf(w1.z, y.z, fmaf(w1.w, y.w, acc[1][b]))));
      acc[2][b] = fmaf(w2.x, y.x, fmaf(w2.y, y.y, fmaf(w2.z, y.z, fmaf(w2.w, y.w, acc[2][b]))));
      acc[3][b] = fmaf(w3.x, y.x, fmaf(w3.y, y.y, fmaf(w3.z, y.z, fmaf(w3.w, y.w, acc[3][b]))));
    }
  }
#pragma unroll
  for (int cc = 0; cc < 4; ++cc)
#pragma unroll
    for (int b = 0; b < 8; ++b) {
      float s = acc[cc][b];
      s += __shfl_xor(s, 1);
      s += __shfl_xor(s, 2);
      s += __shfl_xor(s, 4);
      s += __shfl_xor(s, 8);
      s += __shfl_xor(s, 16);
      s += __shfl_xor(s, 32);
      if (lane == 0) atomicAdd(&r1[b * 512 + c0 + cc], s);
    }
}

// ---------------------------------------------------------------------------
// fc2: one wave per output (b,j): dot-512 + biases
// ---------------------------------------------------------------------------
__global__ __launch_bounds__(256) void fc2_kernel(
    const float* __restrict__ r1, const float* __restrict__ b1,
    const float* __restrict__ W2, const float* __restrict__ b2,
    float* __restrict__ r2)
{
  int wid = blockIdx.x * 4 + (threadIdx.x >> 6);
  int lane = threadIdx.x & 63;
  int b = wid >> 8;
  int j = wid & 255;
  int off = lane * 8;
  float4 ya = *(const float4*)(r1 + b * 512 + off);
  float4 yb = *(const float4*)(r1 + b * 512 + off + 4);
  float4 ba = *(const float4*)(b1 + off);
  float4 bbv = *(const float4*)(b1 + off + 4);
  float4 wa = *(const float4*)(W2 + (size_t)j * 512 + off);
  float4 wb = *(const float4*)(W2 + (size_t)j * 512 + off + 4);
  float p = (ya.x + ba.x) * wa.x + (ya.y + ba.y) * wa.y +
            (ya.z + ba.z) * wa.z + (ya.w + ba.w) * wa.w +
            (yb.x + bbv.x) * wb.x + (yb.y + bbv.y) * wb.y +
            (yb.z + bbv.z) * wb.z + (yb.w + bbv.w) * wb.w;
  p += __shfl_xor(p, 1);
  p += __shfl_xor(p, 2);
  p += __shfl_xor(p, 4);
  p += __shfl_xor(p, 8);
  p += __shfl_xor(p, 16);
  p += __shfl_xor(p, 32);
  if (lane == 0) r2[b * 256 + j] = p + b2[j];
}

// ---------------------------------------------------------------------------
// fc3 + fc4 fused, single block
// ---------------------------------------------------------------------------
__global__ __launch_bounds__(256) void fc34_kernel(
    const float* __restrict__ r2, const float* __restrict__ W3,
    const float* __restrict__ b3, const float* __restrict__ W4,
    const float* __restrict__ b4, float* __restrict__ out)
{
  __shared__ float a3[512];
  int tid = threadIdx.x;
  for (int o = tid; o < 512; o += 256) {
    int b = o >> 6, j = o & 63;
    float s = b3[j];
    const float* rr = r2 + b * 256;
    const float* wr = W3 + j * 256;
    for (int c = 0; c < 256; c += 4) {
      float4 rv = *(const float4*)(rr + c);
      float4 wv = *(const float4*)(wr + c);
      s = fmaf(rv.x, wv.x, fmaf(rv.y, wv.y, fmaf(rv.z, wv.z, fmaf(rv.w, wv.w, s))));
    }
    a3[o] = s;
  }
  __syncthreads();
  if (tid < 64) {
    int b = tid >> 3, j = tid & 7;
    float s = b4[j];
    const float* ar = a3 + b * 64;
    const float* wr = W4 + j * 64;
    for (int c = 0; c < 64; ++c) s = fmaf(ar[c], wr[c], s);
    out[b * 8 + j] = s;
  }
}

// ---------------------------------------------------------------------------
extern "C" void kernel_launch(void* const* d_in, const int* in_sizes, int n_in,
                              void* d_out, int out_size, void* d_ws, size_t ws_size,
                              hipStream_t stream) {
  const float* x      = (const float*)d_in[0];   // [8,5000,24] == [2000][480]
  const float* w_in   = (const float*)d_in[1];   // [2048,512]
  const float* conv_w = (const float*)d_in[2];   // [1024,4]
  const float* conv_b = (const float*)d_in[3];   // [1024]
  const float* w_xp   = (const float*)d_in[4];   // [160,1024]
  const float* w_dt   = (const float*)d_in[5];   // [1024,32]
  const float* b_dt   = (const float*)d_in[6];   // [1024]
  const float* A_log  = (const float*)d_in[7];   // [1024,64]
  const float* Dp     = (const float*)d_in[8];   // [1024]
  const float* w_out  = (const float*)d_in[9];   // [512,1024]
  const float* w1 = (const float*)d_in[10];      // [512,120000]
  const float* b1 = (const float*)d_in[11];
  const float* w2 = (const float*)d_in[12];      // [256,512]
  const float* b2 = (const float*)d_in[13];
  const float* w3 = (const float*)d_in[14];      // [64,256]
  const float* b3 = (const float*)d_in[15];
  const float* w4 = (const float*)d_in[16];      // [8,64]
  const float* b4 = (const float*)d_in[17];
  float* out = (float*)d_out;

  float* ws   = (float*)d_ws;
  float* xz   = ws;                 // [2000][2048]  (x half -> gated y; z half -> silu(z))
  float* xc   = xz + 4096000;       // [2000][1024]
  float* dtb  = xc + 2048000;       // [2000][1024]
  float* ym   = dtb + 2048000;      // [2000][480]  (dead; kept as overread pad)
  float* yfl  = ym + 960000;        // [8][120000]
  float* xdbl = yfl + 960000;       // [2000][160]  (atomic)
  float* r1   = xdbl + 320000;      // [8][512]     (atomic)
  float* r2   = r1 + 4096;          // [8][256]
  (void)ym;

  // zero the atomic accumulators (xdbl + r1, contiguous)
  hipMemsetAsync(xdbl, 0, (320000 + 4096) * sizeof(float), stream);

  // 1. in_proj via bf16 MFMA: xz[2000][2048] = x @ Win^T
  inproj_mfma<<<dim3(2048 / 128, 16, 1), 256, 0, stream>>>(x, w_in, xz);

  // 2. depthwise conv + silu (also silu's the z-half in place), float4
  conv_silu<<<(BL * 256) / 256, 256, 0, stream>>>(xz, conv_w, conv_b, xc);

  // 3. x_proj (split-K=2, atomic): xdbl[2000][160] = xc @ Wxp^T
  gemm_nt<32, 64, 32, 1, 8><<<dim3(3, (BL + 31) / 32, 2), 256, 0, stream>>>(
      xc, w_xp, xdbl, nullptr, BL, 160, 1024, 1024, 1024, 160, 3);

  // 4. dt_proj + softplus: dtb[2000][1024] = softplus(xdbl[:, :32] @ Wdt^T + b_dt)
  gemm_nt<32, 64, 32, 1, 8><<<dim3(1024 / 64, (BL + 31) / 32, 1), 256, 0, stream>>>(
      xdbl, w_dt, dtb, b_dt, BL, 1024, 32, 160, 32, 1024, 1);

  // 5. selective scan -> gated y into xz x-half
  scan_kernel<<<1024, 256, 0, stream>>>(dtb, xc, xdbl, xz, A_log, Dp);

  // 6. out_proj + selu + fused transpose: yfl[8][120000] directly (epi=4)
  gemm_nt<64, 64, 32, 4, 4><<<dim3((KIN + 63) / 64, (BL + 63) / 64, 1), 256, 0, stream>>>(
      xz, w_out, yfl, nullptr, BL, KIN, 1024, 2048, 1024, KIN, 4);

  // 7. fc1 (atomic accumulate into r1)
  fc1_kernel<<<768, 256, 0, stream>>>(yfl, w1, r1);

  // 8. fc2
  fc2_kernel<<<512, 256, 0, stream>>>(r1, b1, w2, b2, r2);

  // 9. fc3 + fc4
  fc34_kernel<<<1, 256, 0, stream>>>(r2, w3, b3, w4, b4, out);
}

// Round 4
// 614.527 us; speedup vs baseline: 1.1522x; 1.0511x over previous
//
#include <hip/hip_runtime.h>
#include <math.h>

#define T_ 250
#define BL 2000        // 8 * 250
#define KIN 480        // P*F = 20*24
#define NFLAT 120000   // 24*5000

typedef __attribute__((ext_vector_type(8))) short short8;
typedef __attribute__((ext_vector_type(4))) float f32x4;

__device__ __forceinline__ float sigmoidf_(float x){ return 1.0f/(1.0f+expf(-x)); }
__device__ __forceinline__ float siluf_(float x){ return x*sigmoidf_(x); }
__device__ __forceinline__ float softplusf_(float x){ return (x > 20.0f) ? x : log1pf(expf(x)); }
__device__ __forceinline__ float seluf_(float x){
  const float sc = 1.0507009873554804934193349852946f;
  const float al = 1.6732632423543772848170429916717f;
  return x > 0.0f ? sc*x : sc*al*expm1f(x);
}
__device__ __forceinline__ unsigned f2bf(float f){   // fp32 -> bf16 bits, RNE
  unsigned u = __builtin_bit_cast(unsigned, f);
  return (u + 0x7FFFu + ((u >> 16) & 1u)) >> 16;
}

// DPP-based add: x + dpp_move(x). Runs on the VALU pipe (no LDS round-trip).
template<int CTRL>
__device__ __forceinline__ float dpp_add(float x) {
  int t = __builtin_amdgcn_update_dpp(0, __builtin_bit_cast(int, x), CTRL, 0xF, 0xF, true);
  return x + __builtin_bit_cast(float, t);
}

// ---------------------------------------------------------------------------
// in_proj via bf16 MFMA: C[2000][2048] = x[2000][480] @ W[2048][512]^T
// 128x128 tile, 4 waves, each wave a 64x64 sub-tile = 4x4 MFMA 16x16x32 frags.
// LDS bf16 [128][40] (pitch 80B). Register double-buffered staging.
// ---------------------------------------------------------------------------
__global__ __launch_bounds__(256) void inproj_mfma(
    const float* __restrict__ x, const float* __restrict__ w,
    float* __restrict__ C)
{
  __shared__ __align__(16) unsigned short As[128 * 40];
  __shared__ __align__(16) unsigned short Bs[128 * 40];
  const int tid = threadIdx.x;
  const int m0 = blockIdx.y * 128;
  const int n0 = blockIdx.x * 128;
  const int wid = tid >> 6, lane = tid & 63;
  const int wr = wid >> 1, wc = wid & 1;     // wave sub-tile (64 rows, 64 cols)
  const int sr = tid >> 1;                   // staging row 0..127
  const int sk = (tid & 1) * 16;             // staging k offset (0 or 16)
  const int fr = lane & 15, fg = lane >> 4;  // fragment row/col + k-group

  float4 pa[4], pb[4];
  auto fetch = [&](int k0) {
    int m = m0 + sr;
    if (m < BL) {
      const float* xp = x + (size_t)m * KIN + k0 + sk;
      pa[0] = *(const float4*)(xp);
      pa[1] = *(const float4*)(xp + 4);
      pa[2] = *(const float4*)(xp + 8);
      pa[3] = *(const float4*)(xp + 12);
    } else {
      pa[0] = pa[1] = pa[2] = pa[3] = make_float4(0.f, 0.f, 0.f, 0.f);
    }
    const float* wp = w + (size_t)(n0 + sr) * 512 + k0 + sk;
    pb[0] = *(const float4*)(wp);
    pb[1] = *(const float4*)(wp + 4);
    pb[2] = *(const float4*)(wp + 8);
    pb[3] = *(const float4*)(wp + 12);
  };
  auto pack2 = [](float a, float b) {
    return f2bf(a) | (f2bf(b) << 16);
  };
  auto stash = [&](unsigned short* S, float4* p) {
    uint4 lo = make_uint4(pack2(p[0].x, p[0].y), pack2(p[0].z, p[0].w),
                          pack2(p[1].x, p[1].y), pack2(p[1].z, p[1].w));
    uint4 hi = make_uint4(pack2(p[2].x, p[2].y), pack2(p[2].z, p[2].w),
                          pack2(p[3].x, p[3].y), pack2(p[3].z, p[3].w));
    *(uint4*)&S[sr * 40 + sk] = lo;
    *(uint4*)&S[sr * 40 + sk + 8] = hi;
  };

  f32x4 acc[4][4];
#pragma unroll
  for (int i = 0; i < 4; ++i)
#pragma unroll
    for (int j = 0; j < 4; ++j) acc[i][j] = (f32x4)(0.0f);

  fetch(0);
  for (int k0 = 0; k0 < KIN; k0 += 32) {
    stash(As, pa);
    stash(Bs, pb);
    __syncthreads();
    if (k0 + 32 < KIN) fetch(k0 + 32);
    short8 av[4], bv[4];
#pragma unroll
    for (int fi = 0; fi < 4; ++fi)
      av[fi] = *(const short8*)&As[(wr * 64 + fi * 16 + fr) * 40 + fg * 8];
#pragma unroll
    for (int fj = 0; fj < 4; ++fj)
      bv[fj] = *(const short8*)&Bs[(wc * 64 + fj * 16 + fr) * 40 + fg * 8];
#pragma unroll
    for (int fi = 0; fi < 4; ++fi)
#pragma unroll
      for (int fj = 0; fj < 4; ++fj)
        acc[fi][fj] = __builtin_amdgcn_mfma_f32_16x16x32_bf16(
            av[fi], bv[fj], acc[fi][fj], 0, 0, 0);
    __syncthreads();
  }

  // C/D layout: col = lane&15, row = (lane>>4)*4 + reg  [guide-verified]
#pragma unroll
  for (int fi = 0; fi < 4; ++fi) {
    int row = m0 + wr * 64 + fi * 16 + fg * 4;
#pragma unroll
    for (int fj = 0; fj < 4; ++fj) {
      int col = n0 + wc * 64 + fj * 16 + fr;
#pragma unroll
      for (int r = 0; r < 4; ++r)
        if (row + r < BL) C[(size_t)(row + r) * 2048 + col] = acc[fi][fj][r];
    }
  }
}

// ---------------------------------------------------------------------------
// 64x64 bf16-MFMA GEMM: C[M,N] = A[M,K] @ W[N,K]^T, fp32 in/out.
// 4 waves (2x2), each wave 32x32 = 2x2 MFMA 16x16x32 frags.
// Supports split-K via gridDim.z.
// EPI 0: atomicAdd into C[m*ldc+n] (C pre-zeroed)
// EPI 1: selu + mamba-transpose store into yfl[b][f*5000 + tt*20 + p]
// ---------------------------------------------------------------------------
template<int EPI>
__global__ __launch_bounds__(256) void gemm_mfma64(
    const float* __restrict__ A, const float* __restrict__ W,
    float* __restrict__ C, int M, int N, int K, int lda, int ldb, int ldc)
{
  __shared__ __align__(16) unsigned short As[64 * 40];
  __shared__ __align__(16) unsigned short Bs[64 * 40];
  const int tid = threadIdx.x;
  const int m0 = blockIdx.y * 64;
  const int n0 = blockIdx.x * 64;
  const int kchunk = K / (int)gridDim.z;
  const int k_begin = blockIdx.z * kchunk;
  const int k_end = k_begin + kchunk;
  const int wid = tid >> 6, lane = tid & 63;
  const int wr = wid >> 1, wc = wid & 1;      // wave 32x32 sub-tile
  const int sr = tid >> 2;                    // staging row 0..63
  const int sk = (tid & 3) * 8;               // staging k-offset 0/8/16/24
  const int fr = lane & 15, fg = lane >> 4;

  float4 pa[2], pb[2];
  auto fetch = [&](int k0) {
    int m = m0 + sr;
    if (m < M) {
      const float* ap = A + (size_t)m * lda + k0 + sk;
      pa[0] = *(const float4*)(ap);
      pa[1] = *(const float4*)(ap + 4);
    } else {
      pa[0] = pa[1] = make_float4(0.f, 0.f, 0.f, 0.f);
    }
    int n = n0 + sr;
    if (n < N) {
      const float* wp = W + (size_t)n * ldb + k0 + sk;
      pb[0] = *(const float4*)(wp);
      pb[1] = *(const float4*)(wp + 4);
    } else {
      pb[0] = pb[1] = make_float4(0.f, 0.f, 0.f, 0.f);
    }
  };
  auto pack2 = [](float a, float b) {
    return f2bf(a) | (f2bf(b) << 16);
  };
  auto stash = [&](unsigned short* S, float4* p) {
    uint4 v = make_uint4(pack2(p[0].x, p[0].y), pack2(p[0].z, p[0].w),
                         pack2(p[1].x, p[1].y), pack2(p[1].z, p[1].w));
    *(uint4*)&S[sr * 40 + sk] = v;
  };

  f32x4 acc[2][2];
#pragma unroll
  for (int i = 0; i < 2; ++i)
#pragma unroll
    for (int j = 0; j < 2; ++j) acc[i][j] = (f32x4)(0.0f);

  fetch(k_begin);
  for (int k0 = k_begin; k0 < k_end; k0 += 32) {
    stash(As, pa);
    stash(Bs, pb);
    __syncthreads();
    if (k0 + 32 < k_end) fetch(k0 + 32);
    short8 av[2], bv[2];
#pragma unroll
    for (int fi = 0; fi < 2; ++fi)
      av[fi] = *(const short8*)&As[(wr * 32 + fi * 16 + fr) * 40 + fg * 8];
#pragma unroll
    for (int fj = 0; fj < 2; ++fj)
      bv[fj] = *(const short8*)&Bs[(wc * 32 + fj * 16 + fr) * 40 + fg * 8];
#pragma unroll
    for (int fi = 0; fi < 2; ++fi)
#pragma unroll
      for (int fj = 0; fj < 2; ++fj)
        acc[fi][fj] = __builtin_amdgcn_mfma_f32_16x16x32_bf16(
            av[fi], bv[fj], acc[fi][fj], 0, 0, 0);
    __syncthreads();
  }

  // C/D layout: col = lane&15, row = (lane>>4)*4 + reg
#pragma unroll
  for (int fi = 0; fi < 2; ++fi) {
    int row0 = m0 + wr * 32 + fi * 16 + fg * 4;
#pragma unroll
    for (int fj = 0; fj < 2; ++fj) {
      int col = n0 + wc * 32 + fj * 16 + fr;
      if (col >= N) continue;
#pragma unroll
      for (int r = 0; r < 4; ++r) {
        int row = row0 + r;
        if (row >= M) continue;
        if constexpr (EPI == 0) {
          atomicAdd(&C[(size_t)row * ldc + col], acc[fi][fj][r]);
        } else {
          int b = row / 250, tt = row - b * 250;
          int p = col / 24, f = col - p * 24;
          C[(size_t)b * NFLAT + (size_t)f * 5000 + tt * 20 + p] =
              seluf_(acc[fi][fj][r]);
        }
      }
    }
  }
}

// ---------------------------------------------------------------------------
// Generic fp32 tiled GEMM (used for dt_proj only now).
// epi: 0 = store, 1 = store softplus(acc + bias[n]), 2 = store selu(acc),
//      3 = atomicAdd (split-K; C pre-zeroed)
// ---------------------------------------------------------------------------
template<int BM, int BN, int BK, int TM, int TN>
__global__ __launch_bounds__(256, 2) void gemm_nt(
    const float* __restrict__ A, const float* __restrict__ W,
    float* __restrict__ C, const float* __restrict__ bias,
    int M, int N, int K, int lda, int ldb, int ldc, int epi)
{
  static_assert(BK == 32, "BK must be 32");
  __shared__ __align__(16) float As[BK][BM + 4];
  __shared__ __align__(16) float Bs[BK][BN + 4];
  constexpr int TNX = BN / TN;
  constexpr int TMX = BM / TM;
  static_assert(TNX * TMX == 256, "256 threads required");
  constexpr int AF4 = BM * BK / 1024;
  constexpr int BF4 = BN * BK / 1024;

  const int tid = threadIdx.x;
  const int tx = tid % TNX;
  const int ty = tid / TNX;
  const int m0 = blockIdx.y * BM;
  const int n0 = blockIdx.x * BN;
  const int kchunk = K / (int)gridDim.z;
  const int k_begin = blockIdx.z * kchunk;
  const int k_end = k_begin + kchunk;

  float4 pa[AF4], pb[BF4];

  auto fetch = [&](int k0) {
#pragma unroll
    for (int i = 0; i < AF4; ++i) {
      int fi = tid + 256 * i;
      int r = fi >> 3;
      int kc = (fi & 7) * 4;
      int m = m0 + r;
      pa[i] = (m < M) ? *(const float4*)(A + (size_t)m * lda + k0 + kc)
                      : make_float4(0.f, 0.f, 0.f, 0.f);
    }
#pragma unroll
    for (int i = 0; i < BF4; ++i) {
      int fi = tid + 256 * i;
      int r = fi >> 3;
      int kc = (fi & 7) * 4;
      int n = n0 + r;
      pb[i] = (n < N) ? *(const float4*)(W + (size_t)n * ldb + k0 + kc)
                      : make_float4(0.f, 0.f, 0.f, 0.f);
    }
  };

  fetch(k_begin);

  float acc[TM][TN];
#pragma unroll
  for (int i = 0; i < TM; ++i)
#pragma unroll
    for (int j = 0; j < TN; ++j) acc[i][j] = 0.0f;

  for (int k0 = k_begin; k0 < k_end; k0 += BK) {
#pragma unroll
    for (int i = 0; i < AF4; ++i) {
      int fi = tid + 256 * i;
      int r = fi >> 3;
      int kc = (fi & 7) * 4;
      As[kc + 0][r] = pa[i].x; As[kc + 1][r] = pa[i].y;
      As[kc + 2][r] = pa[i].z; As[kc + 3][r] = pa[i].w;
    }
#pragma unroll
    for (int i = 0; i < BF4; ++i) {
      int fi = tid + 256 * i;
      int r = fi >> 3;
      int kc = (fi & 7) * 4;
      Bs[kc + 0][r] = pb[i].x; Bs[kc + 1][r] = pb[i].y;
      Bs[kc + 2][r] = pb[i].z; Bs[kc + 3][r] = pb[i].w;
    }
    __syncthreads();
    if (k0 + BK < k_end) fetch(k0 + BK);
#pragma unroll
    for (int kk = 0; kk < BK; ++kk) {
      float a[TM], bb[TN];
      if constexpr ((TM & 3) == 0) {
#pragma unroll
        for (int t = 0; t < TM / 4; ++t) {
          float4 v = *(const float4*)&As[kk][ty * TM + t * 4];
          a[t*4+0] = v.x; a[t*4+1] = v.y; a[t*4+2] = v.z; a[t*4+3] = v.w;
        }
      } else {
#pragma unroll
        for (int i = 0; i < TM; ++i) a[i] = As[kk][ty * TM + i];
      }
      if constexpr ((TN & 3) == 0) {
#pragma unroll
        for (int t = 0; t < TN / 4; ++t) {
          float4 v = *(const float4*)&Bs[kk][tx * TN + t * 4];
          bb[t*4+0] = v.x; bb[t*4+1] = v.y; bb[t*4+2] = v.z; bb[t*4+3] = v.w;
        }
      } else {
#pragma unroll
        for (int j = 0; j < TN; ++j) bb[j] = Bs[kk][tx * TN + j];
      }
#pragma unroll
      for (int i = 0; i < TM; ++i)
#pragma unroll
        for (int j = 0; j < TN; ++j) acc[i][j] = fmaf(a[i], bb[j], acc[i][j]);
    }
    __syncthreads();
  }

#pragma unroll
  for (int i = 0; i < TM; ++i) {
    int m = m0 + ty * TM + i;
    if (m >= M) continue;
    if constexpr ((TN & 3) == 0) {
#pragma unroll
      for (int j0 = 0; j0 < TN; j0 += 4) {
        int n = n0 + tx * TN + j0;
        float v[4];
#pragma unroll
        for (int t = 0; t < 4; ++t) {
          float xv = acc[i][j0 + t];
          if (epi == 1) xv = softplusf_(xv + bias[n + t]);
          else if (epi == 2) xv = seluf_(xv);
          v[t] = xv;
        }
        if (epi == 3) {
#pragma unroll
          for (int t = 0; t < 4; ++t)
            if (n + t < N) atomicAdd(&C[(size_t)m * ldc + n + t], v[t]);
        } else if (n + 3 < N) {
          *(float4*)&C[(size_t)m * ldc + n] = make_float4(v[0], v[1], v[2], v[3]);
        } else {
#pragma unroll
          for (int t = 0; t < 4; ++t)
            if (n + t < N) C[(size_t)m * ldc + n + t] = v[t];
        }
      }
    } else {
#pragma unroll
      for (int j = 0; j < TN; ++j) {
        int n = n0 + tx * TN + j;
        if (n >= N) continue;
        float v = acc[i][j];
        if (epi == 1) v = softplusf_(v + bias[n]);
        else if (epi == 2) v = seluf_(v);
        if (epi == 3) atomicAdd(&C[(size_t)m * ldc + n], v);
        else C[(size_t)m * ldc + n] = v;
      }
    }
  }
}

// ---------------------------------------------------------------------------
// Depthwise causal conv1d (width 4) + bias + silu -> xc, float4-vectorized
// (4 channels per thread). ALSO silu's the z-half of xz in place.
// ---------------------------------------------------------------------------
__global__ __launch_bounds__(256) void conv_silu(
    float* __restrict__ xz, const float* __restrict__ cw,
    const float* __restrict__ cb, float* __restrict__ xc)
{
  int id = blockIdx.x * 256 + threadIdx.x;
  if (id >= BL * 256) return;
  int bl = id >> 8;
  int d4 = (id & 255) * 4;
  int l = bl % T_;
  float* base = xz + (size_t)bl * 2048 + d4;
  float4 x0 = *(const float4*)(base);
  float4 x1 = (l >= 1) ? *(const float4*)(base - 2048) : make_float4(0.f,0.f,0.f,0.f);
  float4 x2 = (l >= 2) ? *(const float4*)(base - 4096) : make_float4(0.f,0.f,0.f,0.f);
  float4 x3 = (l >= 3) ? *(const float4*)(base - 6144) : make_float4(0.f,0.f,0.f,0.f);
  float4 w0 = *(const float4*)(cw + (size_t)d4 * 4);
  float4 w1 = *(const float4*)(cw + (size_t)d4 * 4 + 4);
  float4 w2 = *(const float4*)(cw + (size_t)d4 * 4 + 8);
  float4 w3 = *(const float4*)(cw + (size_t)d4 * 4 + 12);
  float4 cbv = *(const float4*)(cb + d4);
  float4 o;
  o.x = siluf_(fmaf(x3.x, w0.x, fmaf(x2.x, w0.y, fmaf(x1.x, w0.z, fmaf(x0.x, w0.w, cbv.x)))));
  o.y = siluf_(fmaf(x3.y, w1.x, fmaf(x2.y, w1.y, fmaf(x1.y, w1.z, fmaf(x0.y, w1.w, cbv.y)))));
  o.z = siluf_(fmaf(x3.z, w2.x, fmaf(x2.z, w2.y, fmaf(x1.z, w2.z, fmaf(x0.z, w2.w, cbv.z)))));
  o.w = siluf_(fmaf(x3.w, w3.x, fmaf(x2.w, w3.y, fmaf(x1.w, w3.z, fmaf(x0.w, w3.w, cbv.w)))));
  *(float4*)(xc + (size_t)bl * 1024 + d4) = o;
  float4 zv = *(const float4*)(base + 1024);
  zv.x = siluf_(zv.x); zv.y = siluf_(zv.y); zv.z = siluf_(zv.z); zv.w = siluf_(zv.w);
  *(float4*)(base + 1024) = zv;
}

// ---------------------------------------------------------------------------
// Selective scan v4. Wave = 2 channels x (32 lanes x 2 states). 4096 waves.
// DPP reduction; depth-4 prefetch; reads precomputed silu(z).
// ---------------------------------------------------------------------------
__global__ __launch_bounds__(256) void scan_kernel(
    const float* __restrict__ dtb, const float* __restrict__ xc,
    const float* __restrict__ xdbl, float* __restrict__ xz,
    const float* __restrict__ A_log, const float* __restrict__ Dp)
{
  int tid = threadIdx.x;
  int wv = tid >> 6, lane = tid & 63;
  int c = lane >> 5;
  int u = lane & 31;
  int w = blockIdx.x * 4 + wv;
  int b = w >> 9;
  int d = ((w & 511) << 1) + c;
  const float LOG2E = 1.4426950408889634f;
  float2 al = *(const float2*)(A_log + (size_t)d * 64 + u * 2);
  float am0 = -expf(al.x) * LOG2E;
  float am1 = -expf(al.y) * LOG2E;
  float Dv = Dp[d];
  float h0 = 0.f, h1 = 0.f;
  const float* dtp = dtb + (size_t)b * 256000 + d;
  const float* xp  = xc  + (size_t)b * 256000 + d;
  const float* zp  = xz  + (size_t)b * 512000 + 1024 + d;
  float*       yp  = xz  + (size_t)b * 512000 + d;
  const float* bp  = xdbl + (size_t)b * 40000 + 32 + u * 2;
  const float* cp  = bp + 64;

  float dt_f[4], xv_f[4], sz_f[4];
  float2 B_f[4], C_f[4];
#pragma unroll
  for (int i = 0; i < 4; ++i) {
    dt_f[i] = dtp[(size_t)i * 1024];
    xv_f[i] = xp[(size_t)i * 1024];
    sz_f[i] = zp[(size_t)i * 2048];
    B_f[i] = *(const float2*)(bp + (size_t)i * 160);
    C_f[i] = *(const float2*)(cp + (size_t)i * 160);
  }
  const bool outlane = (u == 16);

#pragma unroll 4
  for (int l = 0; l < 252; ++l) {
    int slot = l & 3;
    float dt = dt_f[slot], xv = xv_f[slot], sz = sz_f[slot];
    float2 Bv = B_f[slot], Cv = C_f[slot];
    dt_f[slot] = dtp[(size_t)(l + 4) * 1024];
    xv_f[slot] = xp[(size_t)(l + 4) * 1024];
    sz_f[slot] = zp[(size_t)(l + 4) * 2048];
    B_f[slot]  = *(const float2*)(bp + (size_t)(l + 4) * 160);
    C_f[slot]  = *(const float2*)(cp + (size_t)(l + 4) * 160);

    float dtx = dt * xv;
    h0 = fmaf(h0, exp2f(dt * am0), dtx * Bv.x);
    h1 = fmaf(h1, exp2f(dt * am1), dtx * Bv.y);
    float p = fmaf(h1, Cv.y, h0 * Cv.x);
    p = dpp_add<0xB1>(p);
    p = dpp_add<0x4E>(p);
    p = dpp_add<0x124>(p);
    p = dpp_add<0x128>(p);
    p = dpp_add<0x142>(p);
    if (outlane && l < T_) yp[(size_t)l * 2048] = fmaf(xv, Dv, p) * sz;
  }
}

// ---------------------------------------------------------------------------
// fc1: r1[b][c] += sum_k yfl[b][k] * W1[c][k].
// ---------------------------------------------------------------------------
__global__ __launch_bounds__(256) void fc1_kernel(
    const float* __restrict__ yfl, const float* __restrict__ W,
    float* __restrict__ r1)
{
  int blk = blockIdx.x;
  int ks = blk % 24;
  int cg = blk / 24;
  int wv = threadIdx.x >> 6;
  int lane = threadIdx.x & 63;
  int c0 = cg * 16 + wv * 4;
  const float* W0 = W + (size_t)c0 * NFLAT;
  float acc[4][8];
#pragma unroll
  for (int cc = 0; cc < 4; ++cc)
#pragma unroll
    for (int b = 0; b < 8; ++b) acc[cc][b] = 0.0f;

  int kbase = ks * 5000;
  int kend = kbase + 5000;
  for (int k = kbase + lane * 4; k + 4 <= kend; k += 256) {
    float4 w0 = *(const float4*)(W0 + k);
    float4 w1 = *(const float4*)(W0 + NFLAT + k);
    float4 w2 = *(const float4*)(W0 + 2 * (size_t)NFLAT + k);
    float4 w3 = *(const float4*)(W0 + 3 * (size_t)NFLAT + k);
#pragma unroll
    for (int b = 0; b < 8; ++b) {
      float4 y = *(const float4*)(yfl + (size_t)b * NFLAT + k);
      acc[0][b] = fmaf(w0.x, y.x, fmaf(w0.y, y.y, fmaf(w0.z, y.z, fmaf(w0.w, y.w, acc[0][b]))));
      acc[1][b] = fmaf(w1.x, y.x, fmaf(w1.y, y.y, fmaf(w1.z, y.z, fmaf(w1.w, y.w, acc[1][b]))));
      acc[2][b] = fmaf(w2.x, y.x, fmaf(w2.y, y.y, fmaf(w2.z, y.z, fmaf(w2.w, y.w, acc[2][b]))));
      acc[3][b] = fmaf(w3.x, y.x, fmaf(w3.y, y.y, fmaf(w3.z, y.z, fmaf(w3.w, y.w, acc[3][b]))));
    }
  }
#pragma unroll
  for (int cc = 0; cc < 4; ++cc)
#pragma unroll
    for (int b = 0; b < 8; ++b) {
      float s = acc[cc][b];
      s += __shfl_xor(s, 1);
      s += __shfl_xor(s, 2);
      s += __shfl_xor(s, 4);
      s += __shfl_xor(s, 8);
      s += __shfl_xor(s, 16);
      s += __shfl_xor(s, 32);
      if (lane == 0) atomicAdd(&r1[b * 512 + c0 + cc], s);
    }
}

// ---------------------------------------------------------------------------
// fc2: one wave per output (b,j): dot-512 + biases
// ---------------------------------------------------------------------------
__global__ __launch_bounds__(256) void fc2_kernel(
    const float* __restrict__ r1, const float* __restrict__ b1,
    const float* __restrict__ W2, const float* __restrict__ b2,
    float* __restrict__ r2)
{
  int wid = blockIdx.x * 4 + (threadIdx.x >> 6);
  int lane = threadIdx.x & 63;
  int b = wid >> 8;
  int j = wid & 255;
  int off = lane * 8;
  float4 ya = *(const float4*)(r1 + b * 512 + off);
  float4 yb = *(const float4*)(r1 + b * 512 + off + 4);
  float4 ba = *(const float4*)(b1 + off);
  float4 bbv = *(const float4*)(b1 + off + 4);
  float4 wa = *(const float4*)(W2 + (size_t)j * 512 + off);
  float4 wb = *(const float4*)(W2 + (size_t)j * 512 + off + 4);
  float p = (ya.x + ba.x) * wa.x + (ya.y + ba.y) * wa.y +
            (ya.z + ba.z) * wa.z + (ya.w + ba.w) * wa.w +
            (yb.x + bbv.x) * wb.x + (yb.y + bbv.y) * wb.y +
            (yb.z + bbv.z) * wb.z + (yb.w + bbv.w) * wb.w;
  p += __shfl_xor(p, 1);
  p += __shfl_xor(p, 2);
  p += __shfl_xor(p, 4);
  p += __shfl_xor(p, 8);
  p += __shfl_xor(p, 16);
  p += __shfl_xor(p, 32);
  if (lane == 0) r2[b * 256 + j] = p + b2[j];
}

// ---------------------------------------------------------------------------
// fc3 + fc4 fused, single block
// ---------------------------------------------------------------------------
__global__ __launch_bounds__(256) void fc34_kernel(
    const float* __restrict__ r2, const float* __restrict__ W3,
    const float* __restrict__ b3, const float* __restrict__ W4,
    const float* __restrict__ b4, float* __restrict__ out)
{
  __shared__ float a3[512];
  int tid = threadIdx.x;
  for (int o = tid; o < 512; o += 256) {
    int b = o >> 6, j = o & 63;
    float s = b3[j];
    const float* rr = r2 + b * 256;
    const float* wr = W3 + j * 256;
    for (int c = 0; c < 256; c += 4) {
      float4 rv = *(const float4*)(rr + c);
      float4 wv = *(const float4*)(wr + c);
      s = fmaf(rv.x, wv.x, fmaf(rv.y, wv.y, fmaf(rv.z, wv.z, fmaf(rv.w, wv.w, s))));
    }
    a3[o] = s;
  }
  __syncthreads();
  if (tid < 64) {
    int b = tid >> 3, j = tid & 7;
    float s = b4[j];
    const float* ar = a3 + b * 64;
    const float* wr = W4 + j * 64;
    for (int c = 0; c < 64; ++c) s = fmaf(ar[c], wr[c], s);
    out[b * 8 + j] = s;
  }
}

// ---------------------------------------------------------------------------
extern "C" void kernel_launch(void* const* d_in, const int* in_sizes, int n_in,
                              void* d_out, int out_size, void* d_ws, size_t ws_size,
                              hipStream_t stream) {
  const float* x      = (const float*)d_in[0];   // [8,5000,24] == [2000][480]
  const float* w_in   = (const float*)d_in[1];   // [2048,512]
  const float* conv_w = (const float*)d_in[2];   // [1024,4]
  const float* conv_b = (const float*)d_in[3];   // [1024]
  const float* w_xp   = (const float*)d_in[4];   // [160,1024]
  const float* w_dt   = (const float*)d_in[5];   // [1024,32]
  const float* b_dt   = (const float*)d_in[6];   // [1024]
  const float* A_log  = (const float*)d_in[7];   // [1024,64]
  const float* Dp     = (const float*)d_in[8];   // [1024]
  const float* w_out  = (const float*)d_in[9];   // [512,1024]
  const float* w1 = (const float*)d_in[10];      // [512,120000]
  const float* b1 = (const float*)d_in[11];
  const float* w2 = (const float*)d_in[12];      // [256,512]
  const float* b2 = (const float*)d_in[13];
  const float* w3 = (const float*)d_in[14];      // [64,256]
  const float* b3 = (const float*)d_in[15];
  const float* w4 = (const float*)d_in[16];      // [8,64]
  const float* b4 = (const float*)d_in[17];
  float* out = (float*)d_out;

  float* ws   = (float*)d_ws;
  float* xz   = ws;                 // [2000][2048]  (x half -> gated y; z half -> silu(z))
  float* xc   = xz + 4096000;       // [2000][1024]
  float* dtb  = xc + 2048000;       // [2000][1024]
  float* ym   = dtb + 2048000;      // [2000][480]  (dead; kept as overread pad)
  float* yfl  = ym + 960000;        // [8][120000]
  float* xdbl = yfl + 960000;       // [2000][160]  (atomic)
  float* r1   = xdbl + 320000;      // [8][512]     (atomic)
  float* r2   = r1 + 4096;          // [8][256]
  (void)ym;

  // zero the atomic accumulators (xdbl + r1, contiguous)
  hipMemsetAsync(xdbl, 0, (320000 + 4096) * sizeof(float), stream);

  // 1. in_proj via bf16 MFMA: xz[2000][2048] = x @ Win^T
  inproj_mfma<<<dim3(2048 / 128, 16, 1), 256, 0, stream>>>(x, w_in, xz);

  // 2. depthwise conv + silu (also silu's the z-half in place), float4
  conv_silu<<<(BL * 256) / 256, 256, 0, stream>>>(xz, conv_w, conv_b, xc);

  // 3. x_proj via bf16 MFMA (split-K=2, atomic): xdbl[2000][160] = xc @ Wxp^T
  gemm_mfma64<0><<<dim3(3, 32, 2), 256, 0, stream>>>(
      xc, w_xp, xdbl, BL, 160, 1024, 1024, 1024, 160);

  // 4. dt_proj + softplus: dtb[2000][1024] = softplus(xdbl[:, :32] @ Wdt^T + b_dt)
  gemm_nt<32, 64, 32, 1, 8><<<dim3(1024 / 64, (BL + 31) / 32, 1), 256, 0, stream>>>(
      xdbl, w_dt, dtb, b_dt, BL, 1024, 32, 160, 32, 1024, 1);

  // 5. selective scan -> gated y into xz x-half
  scan_kernel<<<1024, 256, 0, stream>>>(dtb, xc, xdbl, xz, A_log, Dp);

  // 6. out_proj via bf16 MFMA + selu + fused transpose into yfl
  gemm_mfma64<1><<<dim3(8, 32, 1), 256, 0, stream>>>(
      xz, w_out, yfl, BL, 480, 1024, 2048, 1024, 0);

  // 7. fc1 (atomic accumulate into r1)
  fc1_kernel<<<768, 256, 0, stream>>>(yfl, w1, r1);

  // 8. fc2
  fc2_kernel<<<512, 256, 0, stream>>>(r1, b1, w2, b2, r2);

  // 9. fc3 + fc4
  fc34_kernel<<<1, 256, 0, stream>>>(r2, w3, b3, w4, b4, out);
}

// Round 5
// 609.501 us; speedup vs baseline: 1.1617x; 1.0082x over previous
//
#include <hip/hip_runtime.h>
#include <math.h>

#define T_ 250
#define BL 2000        // 8 * 250
#define KIN 480        // P*F = 20*24
#define NFLAT 120000   // 24*5000

typedef __attribute__((ext_vector_type(8))) short short8;
typedef __attribute__((ext_vector_type(4))) float f32x4;

__device__ __forceinline__ float sigmoidf_(float x){ return 1.0f/(1.0f+expf(-x)); }
__device__ __forceinline__ float siluf_(float x){ return x*sigmoidf_(x); }
__device__ __forceinline__ float softplusf_(float x){ return (x > 20.0f) ? x : log1pf(expf(x)); }
__device__ __forceinline__ float seluf_(float x){
  const float sc = 1.0507009873554804934193349852946f;
  const float al = 1.6732632423543772848170429916717f;
  return x > 0.0f ? sc*x : sc*al*expm1f(x);
}
__device__ __forceinline__ unsigned f2bf(float f){   // fp32 -> bf16 bits, RNE
  unsigned u = __builtin_bit_cast(unsigned, f);
  return (u + 0x7FFFu + ((u >> 16) & 1u)) >> 16;
}

// DPP-based add: x + dpp_move(x). Runs on the VALU pipe (no LDS round-trip).
template<int CTRL>
__device__ __forceinline__ float dpp_add(float x) {
  int t = __builtin_amdgcn_update_dpp(0, __builtin_bit_cast(int, x), CTRL, 0xF, 0xF, true);
  return x + __builtin_bit_cast(float, t);
}

// ---------------------------------------------------------------------------
// in_proj via bf16 MFMA: C[2000][2048] = x[2000][480] @ W[2048][512]^T
// 128x64 tile (512 blocks = 2 blocks/CU for barrier-drain overlap), 4 waves,
// each wave a 32x64 strip = 2x4 MFMA 16x16x32 frags.
// LDS bf16 pitch-40 rows (80B). Register double-buffered staging.
// ---------------------------------------------------------------------------
__global__ __launch_bounds__(256) void inproj_mfma(
    const float* __restrict__ x, const float* __restrict__ w,
    float* __restrict__ C)
{
  __shared__ __align__(16) unsigned short As[128 * 40];
  __shared__ __align__(16) unsigned short Bs[64 * 40];
  const int tid = threadIdx.x;
  const int m0 = blockIdx.y * 128;
  const int n0 = blockIdx.x * 64;
  const int wid = tid >> 6, lane = tid & 63;
  const int wr = wid;                         // wave = 32-row strip, all 64 cols
  const int sra = tid >> 1;                   // A staging row 0..127
  const int ska = (tid & 1) * 16;             // A staging k offset (0 or 16)
  const int srb = tid >> 2;                   // B staging row 0..63
  const int skb = (tid & 3) * 8;              // B staging k offset 0/8/16/24
  const int fr = lane & 15, fg = lane >> 4;   // fragment row/col + k-group

  float4 pa[4], pb[2];
  auto fetch = [&](int k0) {
    int m = m0 + sra;
    if (m < BL) {
      const float* xp = x + (size_t)m * KIN + k0 + ska;
      pa[0] = *(const float4*)(xp);
      pa[1] = *(const float4*)(xp + 4);
      pa[2] = *(const float4*)(xp + 8);
      pa[3] = *(const float4*)(xp + 12);
    } else {
      pa[0] = pa[1] = pa[2] = pa[3] = make_float4(0.f, 0.f, 0.f, 0.f);
    }
    const float* wp = w + (size_t)(n0 + srb) * 512 + k0 + skb;
    pb[0] = *(const float4*)(wp);
    pb[1] = *(const float4*)(wp + 4);
  };
  auto pack2 = [](float a, float b) {
    return f2bf(a) | (f2bf(b) << 16);
  };

  f32x4 acc[2][4];
#pragma unroll
  for (int i = 0; i < 2; ++i)
#pragma unroll
    for (int j = 0; j < 4; ++j) acc[i][j] = (f32x4)(0.0f);

  fetch(0);
  for (int k0 = 0; k0 < KIN; k0 += 32) {
    {
      uint4 lo = make_uint4(pack2(pa[0].x, pa[0].y), pack2(pa[0].z, pa[0].w),
                            pack2(pa[1].x, pa[1].y), pack2(pa[1].z, pa[1].w));
      uint4 hi = make_uint4(pack2(pa[2].x, pa[2].y), pack2(pa[2].z, pa[2].w),
                            pack2(pa[3].x, pa[3].y), pack2(pa[3].z, pa[3].w));
      *(uint4*)&As[sra * 40 + ska] = lo;
      *(uint4*)&As[sra * 40 + ska + 8] = hi;
      uint4 bb = make_uint4(pack2(pb[0].x, pb[0].y), pack2(pb[0].z, pb[0].w),
                            pack2(pb[1].x, pb[1].y), pack2(pb[1].z, pb[1].w));
      *(uint4*)&Bs[srb * 40 + skb] = bb;
    }
    __syncthreads();
    if (k0 + 32 < KIN) fetch(k0 + 32);
    short8 av[2], bv[4];
#pragma unroll
    for (int fi = 0; fi < 2; ++fi)
      av[fi] = *(const short8*)&As[(wr * 32 + fi * 16 + fr) * 40 + fg * 8];
#pragma unroll
    for (int fj = 0; fj < 4; ++fj)
      bv[fj] = *(const short8*)&Bs[(fj * 16 + fr) * 40 + fg * 8];
#pragma unroll
    for (int fi = 0; fi < 2; ++fi)
#pragma unroll
      for (int fj = 0; fj < 4; ++fj)
        acc[fi][fj] = __builtin_amdgcn_mfma_f32_16x16x32_bf16(
            av[fi], bv[fj], acc[fi][fj], 0, 0, 0);
    __syncthreads();
  }

  // C/D layout: col = lane&15, row = (lane>>4)*4 + reg  [guide-verified]
#pragma unroll
  for (int fi = 0; fi < 2; ++fi) {
    int row = m0 + wr * 32 + fi * 16 + fg * 4;
#pragma unroll
    for (int fj = 0; fj < 4; ++fj) {
      int col = n0 + fj * 16 + fr;
#pragma unroll
      for (int r = 0; r < 4; ++r)
        if (row + r < BL) C[(size_t)(row + r) * 2048 + col] = acc[fi][fj][r];
    }
  }
}

// ---------------------------------------------------------------------------
// 64x64 bf16-MFMA GEMM: C[M,N] = A[M,K] @ W[N,K]^T, fp32 in/out.
// 4 waves (2x2), each wave 32x32 = 2x2 MFMA 16x16x32 frags. split-K via grid.z.
// EPI 0: atomicAdd into C[m*ldc+n] (C pre-zeroed)
// EPI 1: selu + mamba-transpose store into yfl[b][f*5000 + tt*20 + p]
// EPI 2: softplus(acc + bias[col]) store (dt_proj)
// ---------------------------------------------------------------------------
template<int EPI>
__global__ __launch_bounds__(256) void gemm_mfma64(
    const float* __restrict__ A, const float* __restrict__ W,
    float* __restrict__ C, const float* __restrict__ bias,
    int M, int N, int K, int lda, int ldb, int ldc)
{
  __shared__ __align__(16) unsigned short As[64 * 40];
  __shared__ __align__(16) unsigned short Bs[64 * 40];
  const int tid = threadIdx.x;
  const int m0 = blockIdx.y * 64;
  const int n0 = blockIdx.x * 64;
  const int kchunk = K / (int)gridDim.z;
  const int k_begin = blockIdx.z * kchunk;
  const int k_end = k_begin + kchunk;
  const int wid = tid >> 6, lane = tid & 63;
  const int wr = wid >> 1, wc = wid & 1;      // wave 32x32 sub-tile
  const int sr = tid >> 2;                    // staging row 0..63
  const int sk = (tid & 3) * 8;               // staging k-offset 0/8/16/24
  const int fr = lane & 15, fg = lane >> 4;

  float4 pa[2], pb[2];
  auto fetch = [&](int k0) {
    int m = m0 + sr;
    if (m < M) {
      const float* ap = A + (size_t)m * lda + k0 + sk;
      pa[0] = *(const float4*)(ap);
      pa[1] = *(const float4*)(ap + 4);
    } else {
      pa[0] = pa[1] = make_float4(0.f, 0.f, 0.f, 0.f);
    }
    int n = n0 + sr;
    if (n < N) {
      const float* wp = W + (size_t)n * ldb + k0 + sk;
      pb[0] = *(const float4*)(wp);
      pb[1] = *(const float4*)(wp + 4);
    } else {
      pb[0] = pb[1] = make_float4(0.f, 0.f, 0.f, 0.f);
    }
  };
  auto pack2 = [](float a, float b) {
    return f2bf(a) | (f2bf(b) << 16);
  };
  auto stash = [&](unsigned short* S, float4* p) {
    uint4 v = make_uint4(pack2(p[0].x, p[0].y), pack2(p[0].z, p[0].w),
                         pack2(p[1].x, p[1].y), pack2(p[1].z, p[1].w));
    *(uint4*)&S[sr * 40 + sk] = v;
  };

  f32x4 acc[2][2];
#pragma unroll
  for (int i = 0; i < 2; ++i)
#pragma unroll
    for (int j = 0; j < 2; ++j) acc[i][j] = (f32x4)(0.0f);

  fetch(k_begin);
  for (int k0 = k_begin; k0 < k_end; k0 += 32) {
    stash(As, pa);
    stash(Bs, pb);
    __syncthreads();
    if (k0 + 32 < k_end) fetch(k0 + 32);
    short8 av[2], bv[2];
#pragma unroll
    for (int fi = 0; fi < 2; ++fi)
      av[fi] = *(const short8*)&As[(wr * 32 + fi * 16 + fr) * 40 + fg * 8];
#pragma unroll
    for (int fj = 0; fj < 2; ++fj)
      bv[fj] = *(const short8*)&Bs[(wc * 32 + fj * 16 + fr) * 40 + fg * 8];
#pragma unroll
    for (int fi = 0; fi < 2; ++fi)
#pragma unroll
      for (int fj = 0; fj < 2; ++fj)
        acc[fi][fj] = __builtin_amdgcn_mfma_f32_16x16x32_bf16(
            av[fi], bv[fj], acc[fi][fj], 0, 0, 0);
    __syncthreads();
  }

  // C/D layout: col = lane&15, row = (lane>>4)*4 + reg
#pragma unroll
  for (int fi = 0; fi < 2; ++fi) {
    int row0 = m0 + wr * 32 + fi * 16 + fg * 4;
#pragma unroll
    for (int fj = 0; fj < 2; ++fj) {
      int col = n0 + wc * 32 + fj * 16 + fr;
      if (col >= N) continue;
#pragma unroll
      for (int r = 0; r < 4; ++r) {
        int row = row0 + r;
        if (row >= M) continue;
        if constexpr (EPI == 0) {
          atomicAdd(&C[(size_t)row * ldc + col], acc[fi][fj][r]);
        } else if constexpr (EPI == 1) {
          int b = row / 250, tt = row - b * 250;
          int p = col / 24, f = col - p * 24;
          C[(size_t)b * NFLAT + (size_t)f * 5000 + tt * 20 + p] =
              seluf_(acc[fi][fj][r]);
        } else {
          C[(size_t)row * ldc + col] = softplusf_(acc[fi][fj][r] + bias[col]);
        }
      }
    }
  }
}

// ---------------------------------------------------------------------------
// Depthwise causal conv1d (width 4) + bias + silu -> xc, float4-vectorized
// (4 channels per thread). ALSO silu's the z-half of xz in place.
// ---------------------------------------------------------------------------
__global__ __launch_bounds__(256) void conv_silu(
    float* __restrict__ xz, const float* __restrict__ cw,
    const float* __restrict__ cb, float* __restrict__ xc)
{
  int id = blockIdx.x * 256 + threadIdx.x;
  if (id >= BL * 256) return;
  int bl = id >> 8;
  int d4 = (id & 255) * 4;
  int l = bl % T_;
  float* base = xz + (size_t)bl * 2048 + d4;
  float4 x0 = *(const float4*)(base);
  float4 x1 = (l >= 1) ? *(const float4*)(base - 2048) : make_float4(0.f,0.f,0.f,0.f);
  float4 x2 = (l >= 2) ? *(const float4*)(base - 4096) : make_float4(0.f,0.f,0.f,0.f);
  float4 x3 = (l >= 3) ? *(const float4*)(base - 6144) : make_float4(0.f,0.f,0.f,0.f);
  float4 w0 = *(const float4*)(cw + (size_t)d4 * 4);
  float4 w1 = *(const float4*)(cw + (size_t)d4 * 4 + 4);
  float4 w2 = *(const float4*)(cw + (size_t)d4 * 4 + 8);
  float4 w3 = *(const float4*)(cw + (size_t)d4 * 4 + 12);
  float4 cbv = *(const float4*)(cb + d4);
  float4 o;
  o.x = siluf_(fmaf(x3.x, w0.x, fmaf(x2.x, w0.y, fmaf(x1.x, w0.z, fmaf(x0.x, w0.w, cbv.x)))));
  o.y = siluf_(fmaf(x3.y, w1.x, fmaf(x2.y, w1.y, fmaf(x1.y, w1.z, fmaf(x0.y, w1.w, cbv.y)))));
  o.z = siluf_(fmaf(x3.z, w2.x, fmaf(x2.z, w2.y, fmaf(x1.z, w2.z, fmaf(x0.z, w2.w, cbv.z)))));
  o.w = siluf_(fmaf(x3.w, w3.x, fmaf(x2.w, w3.y, fmaf(x1.w, w3.z, fmaf(x0.w, w3.w, cbv.w)))));
  *(float4*)(xc + (size_t)bl * 1024 + d4) = o;
  float4 zv = *(const float4*)(base + 1024);
  zv.x = siluf_(zv.x); zv.y = siluf_(zv.y); zv.z = siluf_(zv.z); zv.w = siluf_(zv.w);
  *(float4*)(base + 1024) = zv;
}

// ---------------------------------------------------------------------------
// Selective scan v4. Wave = 2 channels x (32 lanes x 2 states). 4096 waves.
// DPP reduction; depth-4 prefetch; reads precomputed silu(z).
// ---------------------------------------------------------------------------
__global__ __launch_bounds__(256) void scan_kernel(
    const float* __restrict__ dtb, const float* __restrict__ xc,
    const float* __restrict__ xdbl, float* __restrict__ xz,
    const float* __restrict__ A_log, const float* __restrict__ Dp)
{
  int tid = threadIdx.x;
  int wv = tid >> 6, lane = tid & 63;
  int c = lane >> 5;
  int u = lane & 31;
  int w = blockIdx.x * 4 + wv;
  int b = w >> 9;
  int d = ((w & 511) << 1) + c;
  const float LOG2E = 1.4426950408889634f;
  float2 al = *(const float2*)(A_log + (size_t)d * 64 + u * 2);
  float am0 = -expf(al.x) * LOG2E;
  float am1 = -expf(al.y) * LOG2E;
  float Dv = Dp[d];
  float h0 = 0.f, h1 = 0.f;
  const float* dtp = dtb + (size_t)b * 256000 + d;
  const float* xp  = xc  + (size_t)b * 256000 + d;
  const float* zp  = xz  + (size_t)b * 512000 + 1024 + d;
  float*       yp  = xz  + (size_t)b * 512000 + d;
  const float* bp  = xdbl + (size_t)b * 40000 + 32 + u * 2;
  const float* cp  = bp + 64;

  float dt_f[4], xv_f[4], sz_f[4];
  float2 B_f[4], C_f[4];
#pragma unroll
  for (int i = 0; i < 4; ++i) {
    dt_f[i] = dtp[(size_t)i * 1024];
    xv_f[i] = xp[(size_t)i * 1024];
    sz_f[i] = zp[(size_t)i * 2048];
    B_f[i] = *(const float2*)(bp + (size_t)i * 160);
    C_f[i] = *(const float2*)(cp + (size_t)i * 160);
  }
  const bool outlane = (u == 16);

#pragma unroll 4
  for (int l = 0; l < 252; ++l) {
    int slot = l & 3;
    float dt = dt_f[slot], xv = xv_f[slot], sz = sz_f[slot];
    float2 Bv = B_f[slot], Cv = C_f[slot];
    dt_f[slot] = dtp[(size_t)(l + 4) * 1024];
    xv_f[slot] = xp[(size_t)(l + 4) * 1024];
    sz_f[slot] = zp[(size_t)(l + 4) * 2048];
    B_f[slot]  = *(const float2*)(bp + (size_t)(l + 4) * 160);
    C_f[slot]  = *(const float2*)(cp + (size_t)(l + 4) * 160);

    float dtx = dt * xv;
    h0 = fmaf(h0, exp2f(dt * am0), dtx * Bv.x);
    h1 = fmaf(h1, exp2f(dt * am1), dtx * Bv.y);
    float p = fmaf(h1, Cv.y, h0 * Cv.x);
    p = dpp_add<0xB1>(p);
    p = dpp_add<0x4E>(p);
    p = dpp_add<0x124>(p);
    p = dpp_add<0x128>(p);
    p = dpp_add<0x142>(p);
    if (outlane && l < T_) yp[(size_t)l * 2048] = fmaf(xv, Dv, p) * sz;
  }
}

// ---------------------------------------------------------------------------
// fc1: r1[b][c] += sum_k yfl[b][k] * W1[c][k].
// ---------------------------------------------------------------------------
__global__ __launch_bounds__(256) void fc1_kernel(
    const float* __restrict__ yfl, const float* __restrict__ W,
    float* __restrict__ r1)
{
  int blk = blockIdx.x;
  int ks = blk % 24;
  int cg = blk / 24;
  int wv = threadIdx.x >> 6;
  int lane = threadIdx.x & 63;
  int c0 = cg * 16 + wv * 4;
  const float* W0 = W + (size_t)c0 * NFLAT;
  float acc[4][8];
#pragma unroll
  for (int cc = 0; cc < 4; ++cc)
#pragma unroll
    for (int b = 0; b < 8; ++b) acc[cc][b] = 0.0f;

  int kbase = ks * 5000;
  int kend = kbase + 5000;
  for (int k = kbase + lane * 4; k + 4 <= kend; k += 256) {
    float4 w0 = *(const float4*)(W0 + k);
    float4 w1 = *(const float4*)(W0 + NFLAT + k);
    float4 w2 = *(const float4*)(W0 + 2 * (size_t)NFLAT + k);
    float4 w3 = *(const float4*)(W0 + 3 * (size_t)NFLAT + k);
#pragma unroll
    for (int b = 0; b < 8; ++b) {
      float4 y = *(const float4*)(yfl + (size_t)b * NFLAT + k);
      acc[0][b] = fmaf(w0.x, y.x, fmaf(w0.y, y.y, fmaf(w0.z, y.z, fmaf(w0.w, y.w, acc[0][b]))));
      acc[1][b] = fmaf(w1.x, y.x, fmaf(w1.y, y.y, fmaf(w1.z, y.z, fmaf(w1.w, y.w, acc[1][b]))));
      acc[2][b] = fmaf(w2.x, y.x, fmaf(w2.y, y.y, fmaf(w2.z, y.z, fmaf(w2.w, y.w, acc[2][b]))));
      acc[3][b] = fmaf(w3.x, y.x, fmaf(w3.y, y.y, fmaf(w3.z, y.z, fmaf(w3.w, y.w, acc[3][b]))));
    }
  }
#pragma unroll
  for (int cc = 0; cc < 4; ++cc)
#pragma unroll
    for (int b = 0; b < 8; ++b) {
      float s = acc[cc][b];
      s += __shfl_xor(s, 1);
      s += __shfl_xor(s, 2);
      s += __shfl_xor(s, 4);
      s += __shfl_xor(s, 8);
      s += __shfl_xor(s, 16);
      s += __shfl_xor(s, 32);
      if (lane == 0) atomicAdd(&r1[b * 512 + c0 + cc], s);
    }
}

// ---------------------------------------------------------------------------
// fc2: one wave per output (b,j): dot-512 + biases
// ---------------------------------------------------------------------------
__global__ __launch_bounds__(256) void fc2_kernel(
    const float* __restrict__ r1, const float* __restrict__ b1,
    const float* __restrict__ W2, const float* __restrict__ b2,
    float* __restrict__ r2)
{
  int wid = blockIdx.x * 4 + (threadIdx.x >> 6);
  int lane = threadIdx.x & 63;
  int b = wid >> 8;
  int j = wid & 255;
  int off = lane * 8;
  float4 ya = *(const float4*)(r1 + b * 512 + off);
  float4 yb = *(const float4*)(r1 + b * 512 + off + 4);
  float4 ba = *(const float4*)(b1 + off);
  float4 bbv = *(const float4*)(b1 + off + 4);
  float4 wa = *(const float4*)(W2 + (size_t)j * 512 + off);
  float4 wb = *(const float4*)(W2 + (size_t)j * 512 + off + 4);
  float p = (ya.x + ba.x) * wa.x + (ya.y + ba.y) * wa.y +
            (ya.z + ba.z) * wa.z + (ya.w + ba.w) * wa.w +
            (yb.x + bbv.x) * wb.x + (yb.y + bbv.y) * wb.y +
            (yb.z + bbv.z) * wb.z + (yb.w + bbv.w) * wb.w;
  p += __shfl_xor(p, 1);
  p += __shfl_xor(p, 2);
  p += __shfl_xor(p, 4);
  p += __shfl_xor(p, 8);
  p += __shfl_xor(p, 16);
  p += __shfl_xor(p, 32);
  if (lane == 0) r2[b * 256 + j] = p + b2[j];
}

// ---------------------------------------------------------------------------
// fc3 + fc4 fused, single block
// ---------------------------------------------------------------------------
__global__ __launch_bounds__(256) void fc34_kernel(
    const float* __restrict__ r2, const float* __restrict__ W3,
    const float* __restrict__ b3, const float* __restrict__ W4,
    const float* __restrict__ b4, float* __restrict__ out)
{
  __shared__ float a3[512];
  int tid = threadIdx.x;
  for (int o = tid; o < 512; o += 256) {
    int b = o >> 6, j = o & 63;
    float s = b3[j];
    const float* rr = r2 + b * 256;
    const float* wr = W3 + j * 256;
    for (int c = 0; c < 256; c += 4) {
      float4 rv = *(const float4*)(rr + c);
      float4 wv = *(const float4*)(wr + c);
      s = fmaf(rv.x, wv.x, fmaf(rv.y, wv.y, fmaf(rv.z, wv.z, fmaf(rv.w, wv.w, s))));
    }
    a3[o] = s;
  }
  __syncthreads();
  if (tid < 64) {
    int b = tid >> 3, j = tid & 7;
    float s = b4[j];
    const float* ar = a3 + b * 64;
    const float* wr = W4 + j * 64;
    for (int c = 0; c < 64; ++c) s = fmaf(ar[c], wr[c], s);
    out[b * 8 + j] = s;
  }
}

// ---------------------------------------------------------------------------
extern "C" void kernel_launch(void* const* d_in, const int* in_sizes, int n_in,
                              void* d_out, int out_size, void* d_ws, size_t ws_size,
                              hipStream_t stream) {
  const float* x      = (const float*)d_in[0];   // [8,5000,24] == [2000][480]
  const float* w_in   = (const float*)d_in[1];   // [2048,512]
  const float* conv_w = (const float*)d_in[2];   // [1024,4]
  const float* conv_b = (const float*)d_in[3];   // [1024]
  const float* w_xp   = (const float*)d_in[4];   // [160,1024]
  const float* w_dt   = (const float*)d_in[5];   // [1024,32]
  const float* b_dt   = (const float*)d_in[6];   // [1024]
  const float* A_log  = (const float*)d_in[7];   // [1024,64]
  const float* Dp     = (const float*)d_in[8];   // [1024]
  const float* w_out  = (const float*)d_in[9];   // [512,1024]
  const float* w1 = (const float*)d_in[10];      // [512,120000]
  const float* b1 = (const float*)d_in[11];
  const float* w2 = (const float*)d_in[12];      // [256,512]
  const float* b2 = (const float*)d_in[13];
  const float* w3 = (const float*)d_in[14];      // [64,256]
  const float* b3 = (const float*)d_in[15];
  const float* w4 = (const float*)d_in[16];      // [8,64]
  const float* b4 = (const float*)d_in[17];
  float* out = (float*)d_out;

  float* ws   = (float*)d_ws;
  float* xz   = ws;                 // [2000][2048]  (x half -> gated y; z half -> silu(z))
  float* xc   = xz + 4096000;       // [2000][1024]
  float* dtb  = xc + 2048000;       // [2000][1024]
  float* ym   = dtb + 2048000;      // [2000][480]  (dead; kept as overread pad)
  float* yfl  = ym + 960000;        // [8][120000]
  float* xdbl = yfl + 960000;       // [2000][160]  (atomic)
  float* r1   = xdbl + 320000;      // [8][512]     (atomic)
  float* r2   = r1 + 4096;          // [8][256]
  (void)ym;

  // zero the atomic accumulators (xdbl + r1, contiguous)
  hipMemsetAsync(xdbl, 0, (320000 + 4096) * sizeof(float), stream);

  // 1. in_proj via bf16 MFMA (128x64 tile, 512 blocks = 2 blocks/CU)
  inproj_mfma<<<dim3(2048 / 64, 16, 1), 256, 0, stream>>>(x, w_in, xz);

  // 2. depthwise conv + silu (also silu's the z-half in place), float4
  conv_silu<<<(BL * 256) / 256, 256, 0, stream>>>(xz, conv_w, conv_b, xc);

  // 3. x_proj via bf16 MFMA (split-K=4, atomic): xdbl[2000][160] = xc @ Wxp^T
  gemm_mfma64<0><<<dim3(3, 32, 4), 256, 0, stream>>>(
      xc, w_xp, xdbl, nullptr, BL, 160, 1024, 1024, 1024, 160);

  // 4. dt_proj via bf16 MFMA (K=32 = single k-step) + softplus + bias
  gemm_mfma64<2><<<dim3(1024 / 64, 32, 1), 256, 0, stream>>>(
      xdbl, w_dt, dtb, b_dt, BL, 1024, 32, 160, 32, 1024);

  // 5. selective scan -> gated y into xz x-half
  scan_kernel<<<1024, 256, 0, stream>>>(dtb, xc, xdbl, xz, A_log, Dp);

  // 6. out_proj via bf16 MFMA + selu + fused transpose into yfl
  gemm_mfma64<1><<<dim3(8, 32, 1), 256, 0, stream>>>(
      xz, w_out, yfl, nullptr, BL, 480, 1024, 2048, 1024, 0);

  // 7. fc1 (atomic accumulate into r1)
  fc1_kernel<<<768, 256, 0, stream>>>(yfl, w1, r1);

  // 8. fc2
  fc2_kernel<<<512, 256, 0, stream>>>(r1, b1, w2, b2, r2);

  // 9. fc3 + fc4
  fc34_kernel<<<1, 256, 0, stream>>>(r2, w3, b3, w4, b4, out);
}